// Round 20
// baseline (941.625 us; speedup 1.0000x reference)
//
#include <hip/hip_runtime.h>
#include <hip/hip_bf16.h>
#include <math.h>
#include <stdint.h>

#define FRAME 960
#define NFFT  3840
#define NWIN  1024
#define NFREQ 1921
#define NB    8
#define LF    200
#define LW    192000
#define CIN   450
#define CI    512
#define HID   1536
#define NL    6
#define NCH   188
#define NK2   3842
#define MTOT  1600
#define MB2   3200   // both trunks batched
#define SWID  3968   // padded spec width
#define MPAD  1664   // padded frame rows for DFT

typedef __attribute__((ext_vector_type(8))) short short8v;
typedef __attribute__((ext_vector_type(4))) float f32x4;
typedef __attribute__((address_space(3))) uint32_t lds_u32;
typedef const __attribute__((address_space(1))) uint32_t glb_u32;

// ---------------- threefry (JAX partitionable) ----------------
__device__ __forceinline__ uint32_t rotl32(uint32_t v, int r) { return (v << r) | (v >> (32 - r)); }
__device__ __forceinline__ void threefry2x32(uint32_t k0, uint32_t k1, uint32_t& x0, uint32_t& x1) {
  uint32_t ks2 = k0 ^ k1 ^ 0x1BD11BDAu;
  x0 += k0; x1 += k1;
#define TFR(r) { x0 += x1; x1 = rotl32(x1, r); x1 ^= x0; }
  TFR(13) TFR(15) TFR(26) TFR(6)  x0 += k1;  x1 += ks2 + 1u;
  TFR(17) TFR(29) TFR(16) TFR(24) x0 += ks2; x1 += k0 + 2u;
  TFR(13) TFR(15) TFR(26) TFR(6)  x0 += k0;  x1 += k1 + 3u;
  TFR(17) TFR(29) TFR(16) TFR(24) x0 += k1;  x1 += ks2 + 4u;
  TFR(13) TFR(15) TFR(26) TFR(6)  x0 += ks2; x1 += k0 + 5u;
#undef TFR
}
__device__ __forceinline__ float noiseval(int b, int m) {
  if (m < 0) m = -m;
  if (m >= LW) m = 2 * LW - 2 - m;
  uint32_t x0 = 0u, x1 = (uint32_t)(b * LW + m);
  threefry2x32(0u, 123u, x0, x1);
  uint32_t bits = x0 ^ x1;
  return __uint_as_float((bits >> 9) | 0x3f800000u) - 1.0f;
}
__device__ __forceinline__ float winf(int j) {
  return 0.5f - 0.5f * cosf((6.283185307179586f * (float)j) / 3840.0f);
}
__device__ __forceinline__ unsigned short f2bf(float v) {
  uint32_t b = __float_as_uint(v);
  return (unsigned short)((b + 0x7FFFu + ((b >> 16) & 1u)) >> 16);
}
__device__ __forceinline__ float bf2f(unsigned short h) {
  return __uint_as_float(((uint32_t)h) << 16);
}
__device__ __forceinline__ uint32_t pack2(float a, float b, bool lo) {
  unsigned short ha = f2bf(a), hb = f2bf(b);
  if (!lo) return (uint32_t)ha | ((uint32_t)hb << 16);
  return (uint32_t)f2bf(a - bf2f(ha)) | ((uint32_t)f2bf(b - bf2f(hb)) << 16);
}
__device__ __forceinline__ int xcd_remap(int lin, int nwg) {
  int q = nwg >> 3, r = nwg & 7;
  int xcd = lin & 7, base = lin >> 3;
  int start = (xcd < r) ? xcd * (q + 1) : r * (q + 1) + (xcd - r) * q;
  return start + base;
}

// ---------------- cos table (3840 f32), bit-matching winf's cos argument ----------------
__global__ void ctab_fill(float* __restrict__ ct) {
  int j = blockIdx.x * 256 + threadIdx.x;
  if (j < NFFT) ct[j] = cosf((6.283185307179586f * (float)j) / 3840.0f);
}

// ---------------- xin packed (hi only), duplicated for both trunks ----------------
__global__ void build_xin_pk(const float* __restrict__ content, const float* __restrict__ f0,
                             const float* __restrict__ energy, const float* __restrict__ spk,
                             uint32_t* __restrict__ PH) {
  int idx = blockIdx.x * 256 + threadIdx.x;
  if (idx >= MB2 * 240) return;
  int row = idx / 240, cp = idx % 240;
  int rb = row % MTOT;
  int b = rb / LF, l = rb % LF;
  float v2[2];
#pragma unroll
  for (int u = 0; u < 2; ++u) {
    int c = cp * 2 + u;
    float v = 0.f;
    if (c < 192)       v = content[((size_t)b * 192 + c) * LF + l];
    else if (c < 448)  v = spk[b * 256 + (c - 192)];
    else if (c == 448) v = logf(fmaxf(f0[b * LF + l], 0.0f) + 1e-6f);
    else if (c == 449) v = energy[b * LF + l];
    v2[u] = v;
  }
  PH[idx] = pack2(v2[0], v2[1], false);
}

// ---------------- weight pack (single set, hi only) ----------------
__global__ void pack_w(const float* __restrict__ W, uint32_t* __restrict__ PH,
                       int M, int K, int Kp2, int total) {
  int idx = blockIdx.x * 256 + threadIdx.x;
  if (idx >= total) return;
  int m = idx / Kp2, kp = idx % Kp2;
  int k = kp * 2;
  float v0 = (m < M && k < K) ? W[(size_t)m * K + k] : 0.f;
  float v1 = (m < M && (k + 1) < K) ? W[(size_t)m * K + k + 1] : 0.f;
  PH[idx] = pack2(v0, v1, false);
}

// ---------------- weight pack (dual set, one dispatch, hi only) ----------------
__global__ void pack_w2(const float* __restrict__ Ws, const float* __restrict__ Wf,
                        uint32_t* __restrict__ PH, int M, int K, int Kp2, int total) {
  int idx = blockIdx.x * 256 + threadIdx.x;
  if (idx >= 2 * total) return;
  int half = idx >= total;
  const float* W = half ? Wf : Ws;
  int t = idx - half * total;
  int m = t / Kp2, kp = t % Kp2;
  int k = kp * 2;
  float v0 = (m < M && k < K) ? W[(size_t)m * K + k] : 0.f;
  float v1 = (m < M && (k + 1) < K) ? W[(size_t)m * K + k + 1] : 0.f;
  PH[idx] = pack2(v0, v1, false);
}

// ---------------- weight pack (dual set, N layers, one dispatch, hi only) ----------------
__global__ void pack_wN(const float* __restrict__ Ws, const float* __restrict__ Wf, size_t lstride,
                        uint32_t* __restrict__ PH, int M, int K, int Kp2, int perset, int total) {
  int idx = blockIdx.x * 256 + threadIdx.x;
  if (idx >= total) return;
  int l = idx / (2 * perset);
  int r = idx - l * 2 * perset;
  int half = r >= perset;
  const float* W = (half ? Wf : Ws) + (size_t)l * lstride;
  int t = r - half * perset;
  int m = t / Kp2, kp = t % Kp2;
  int k = kp * 2;
  float v0 = (m < M && k < K) ? W[(size_t)m * K + k] : 0.f;
  float v1 = (m < M && (k + 1) < K) ? W[(size_t)m * K + k + 1] : 0.f;
  PH[idx] = pack2(v0, v1, false);
}

// ---------------- single-bf16 NT GEMM, 64x64 tile, dual-weight-set batched ----------------
// staging spread across all 4 waves (opsel = w>>1 selects operand, whalf = w&1 selects chunks)
__global__ __launch_bounds__(256) void gemm_bf(
    const uint16_t* __restrict__ WH, const uint16_t* __restrict__ XH,
    const float* __restrict__ bias, const float* __restrict__ bias2,
    const float* __restrict__ res,
    float* __restrict__ outF, uint16_t* __restrict__ outH,
    int M, int Kp, int mtiles, int ntiles, int mode, int act, int nsp, size_t woff)
{
  __shared__ __align__(16) char smem[2][2][4096];
  int nwg = mtiles * ntiles;
  int wg = xcd_remap(blockIdx.x, nwg);
  int mtile = wg / ntiles, ntile = wg % ntiles;
  int m0 = mtile * 64, n0 = ntile * 64;
  int tid = threadIdx.x;
  int lane = tid & 63, w = tid >> 6;
  int wm = w >> 1, wn = w & 1;
  int rowg = Kp >> 3;
  int phases = Kp >> 5;

  int opsel = w >> 1, whalf = w & 1;
  const uint16_t* gb = (opsel == 0) ? WH : XH;
  if (opsel == 0 && ntile >= nsp) gb += woff;
  int row0 = (opsel == 0) ? m0 : n0;
  f32x4 acc[2][2];
#pragma unroll
  for (int i = 0; i < 2; ++i)
#pragma unroll
    for (int j = 0; j < 2; ++j) acc[i][j] = (f32x4){0.f, 0.f, 0.f, 0.f};

  auto stage = [&](int buf, int p) {
    int kg0 = p * 4;
#pragma unroll
    for (int c = 0; c < 2; ++c) {
      int i = whalf * 2 + c;
      int r = i * 16 + (lane >> 2);
      int scg = lane & 3;
      int sgsel = scg ^ (((lane >> 2) >> 1) & 3);
      const uint16_t* src = gb + (size_t)(row0 + r) * rowg * 8 + (size_t)(kg0 + sgsel) * 8;
      __builtin_amdgcn_global_load_lds((glb_u32*)src, (lds_u32*)(&smem[buf][opsel][0] + i * 1024), 16, 0, 0);
    }
  };

  stage(0, 0);
  __syncthreads();
  int fr = lane & 15, fg = lane >> 4;
  int fsw = ((fr >> 1) & 3);
  int aoff0 = (wm * 32 + fr) * 64 + (fg ^ fsw) * 16;
  int aoff1 = (wm * 32 + 16 + fr) * 64 + (fg ^ fsw) * 16;
  int boff0 = (wn * 32 + fr) * 64 + (fg ^ fsw) * 16;
  int boff1 = (wn * 32 + 16 + fr) * 64 + (fg ^ fsw) * 16;

  for (int p = 0; p < phases; ++p) {
    int cur = p & 1;
    if (p + 1 < phases) stage(cur ^ 1, p + 1);
    short8v ah0 = *(const short8v*)(&smem[cur][0][0] + aoff0);
    short8v ah1 = *(const short8v*)(&smem[cur][0][0] + aoff1);
    short8v bh0 = *(const short8v*)(&smem[cur][1][0] + boff0);
    short8v bh1 = *(const short8v*)(&smem[cur][1][0] + boff1);
    acc[0][0] = __builtin_amdgcn_mfma_f32_16x16x32_bf16(ah0, bh0, acc[0][0], 0, 0, 0);
    acc[0][1] = __builtin_amdgcn_mfma_f32_16x16x32_bf16(ah0, bh1, acc[0][1], 0, 0, 0);
    acc[1][0] = __builtin_amdgcn_mfma_f32_16x16x32_bf16(ah1, bh0, acc[1][0], 0, 0, 0);
    acc[1][1] = __builtin_amdgcn_mfma_f32_16x16x32_bf16(ah1, bh1, acc[1][1], 0, 0, 0);
    __syncthreads();
  }

#pragma unroll
  for (int mi = 0; mi < 2; ++mi)
#pragma unroll
    for (int ni = 0; ni < 2; ++ni)
#pragma unroll
      for (int r = 0; r < 4; ++r) {
        int m = m0 + wm * 32 + mi * 16 + ((lane >> 4) << 2) + r;
        int n = n0 + wn * 32 + ni * 16 + (lane & 15);
        if (m >= M) continue;
        float v = acc[mi][ni][r];
        if (bias) v += (bias2 && n >= nsp * 64) ? bias2[m] : bias[m];
        if (act == 1)      v = 0.5f * v * (1.0f + erff(v * 0.7071067811865475f));
        else if (act == 2) v = (v > 0.f ? v : expm1f(v)) + 1.0f;
        if (mode == 0) {
          if (res) v += res[(size_t)n * M + m];
          outF[(size_t)n * M + m] = v;
        } else if (mode == 1) {
          outH[(size_t)n * M + m] = f2bf(v);
        } else {  // 2: KER bf16 (NFREQ row stride)
          outH[(size_t)n * NFREQ + m] = f2bf(v);
        }
      }
}

// ---------------- fwd DFT GEMM: 128x64 tile, single-bf16 (grid 13x62 for occupancy) ----------------
__global__ __launch_bounds__(256) void gemm_fwd128(
    const uint16_t* __restrict__ AH, const uint16_t* __restrict__ TH,
    const uint16_t* __restrict__ KERH, uint16_t* __restrict__ SH)
{
  __shared__ __align__(16) char smem[2][12288];   // A 8KB | B 4KB per buffer
  int wg = xcd_remap(blockIdx.x, 62 * 13);
  int ntile = wg / 13, mtile = wg % 13;   // m-inner: T-tile L2-resident
  int m0 = mtile * 128, n0 = ntile * 64;
  int tid = threadIdx.x;
  int lane = tid & 63, w = tid >> 6;
  int wm = w >> 1, wn = w & 1;
  f32x4 acc[4][2];
#pragma unroll
  for (int i = 0; i < 4; ++i)
#pragma unroll
    for (int j = 0; j < 2; ++j) acc[i][j] = (f32x4){0.f, 0.f, 0.f, 0.f};

  auto stage = [&](int buf, int p) {
    if (w < 2) {
#pragma unroll
      for (int i = 0; i < 4; ++i) {
        int ci = w * 4 + i;             // A chunks 0..7
        int gl = ci * 64 + lane;
        int row = gl >> 2, cg = gl & 3;
        int sg = cg ^ ((row >> 1) & 3);
        const uint16_t* src = AH + (size_t)(m0 + row) * 3840 + p * 32 + sg * 8;
        __builtin_amdgcn_global_load_lds((glb_u32*)src, (lds_u32*)(&smem[buf][0] + ci * 1024), 16, 0, 0);
      }
    } else {
#pragma unroll
      for (int i = 0; i < 2; ++i) {
        int ci = (w - 2) * 2 + i;       // B chunks 0..3
        int gl = ci * 64 + lane;
        int row = gl >> 2, cg = gl & 3;
        int sg = cg ^ ((row >> 1) & 3);
        const uint16_t* src = TH + (size_t)(n0 + row) * 3840 + p * 32 + sg * 8;
        __builtin_amdgcn_global_load_lds((glb_u32*)src, (lds_u32*)(&smem[buf][8192] + ci * 1024), 16, 0, 0);
      }
    }
  };

  stage(0, 0);
  __syncthreads();
  int fr = lane & 15, fg = lane >> 4;

  for (int p = 0; p < 120; ++p) {
    int cur = p & 1;
    if (p + 1 < 120) stage(cur ^ 1, p + 1);
    short8v a_h[4], b_h[2];
#pragma unroll
    for (int q = 0; q < 4; ++q) {
      int ra = wm * 64 + q * 16 + fr;
      a_h[q] = *(const short8v*)(&smem[cur][0] + ra * 64 + ((fg ^ ((ra >> 1) & 3)) << 4));
    }
#pragma unroll
    for (int s = 0; s < 2; ++s) {
      int rb = wn * 32 + s * 16 + fr;
      b_h[s] = *(const short8v*)(&smem[cur][8192] + rb * 64 + ((fg ^ ((rb >> 1) & 3)) << 4));
    }
#pragma unroll
    for (int mi = 0; mi < 4; ++mi)
#pragma unroll
      for (int ni = 0; ni < 2; ++ni)
        acc[mi][ni] = __builtin_amdgcn_mfma_f32_16x16x32_bf16(a_h[mi], b_h[ni], acc[mi][ni], 0, 0, 0);
    __syncthreads();
  }

#pragma unroll
  for (int mi = 0; mi < 4; ++mi)
#pragma unroll
    for (int ni = 0; ni < 2; ++ni)
#pragma unroll
      for (int r = 0; r < 4; ++r) {
        int m = m0 + wm * 64 + mi * 16 + ((lane >> 4) << 2) + r;
        int n = n0 + wn * 32 + ni * 16 + (lane & 15);
        if (m < MTOT) {
          float o = 0.f;
          if (n < NK2) {
            int k = n >> 1;
            float kv = bf2f(KERH[(size_t)m * NFREQ + k]);
            bool edge = (k == 0) || (k == 1920);
            float mult = edge ? (1.0f / NFFT) : (2.0f / NFFT);
            o = acc[mi][ni][r] * kv * mult;
            if ((n & 1) && edge) o = 0.f;
          }
          SH[(size_t)m * SWID + n] = f2bf(o);
        }
      }
}

// ---------------- transposed twiddle V[j][k2] via cos table (hi only; overwrites T after fwd) ----------------
__global__ void twfill_v(const float* __restrict__ ct, uint32_t* __restrict__ VH) {
  int idx = blockIdx.x * 256 + threadIdx.x;
  if (idx >= NFFT * (SWID / 2)) return;
  int j = idx / (SWID / 2), kp = idx % (SWID / 2);
  float v2[2] = {0.f, 0.f};
#pragma unroll
  for (int u = 0; u < 2; ++u) {
    int k2 = kp * 2 + u;
    if (k2 < NK2) {
      int k = k2 >> 1;
      int m = (j * k) % NFFT;
      m += (k2 & 1) * 960;               // -sin(x) = cos(x + pi/2)
      if (m >= NFFT) m -= NFFT;
      v2[u] = ct[m];
    }
  }
  VH[idx] = pack2(v2[0], v2[1], false);
}

// ---------------- inverse DFT as pure NT GEMM: 128x64 tile (grid 60x13); window via ctab ----------------
__global__ __launch_bounds__(256) void gemm_invNT(
    const uint16_t* __restrict__ SH, const uint16_t* __restrict__ VH,
    const float* __restrict__ ct, float* __restrict__ ft)
{
  __shared__ __align__(16) char smem[2][12288];
  int wg = xcd_remap(blockIdx.x, 60 * 13);
  int ntile = wg / 13, mtile = wg % 13;   // m-inner: V-tile L2-resident
  int m0 = mtile * 128, n0 = ntile * 64;
  int tid = threadIdx.x;
  int lane = tid & 63, w = tid >> 6;
  int wm = w >> 1, wn = w & 1;
  f32x4 acc[4][2];
#pragma unroll
  for (int i = 0; i < 4; ++i)
#pragma unroll
    for (int j = 0; j < 2; ++j) acc[i][j] = (f32x4){0.f, 0.f, 0.f, 0.f};

  auto stage = [&](int buf, int p) {
    if (w < 2) {
#pragma unroll
      for (int i = 0; i < 4; ++i) {
        int ci = w * 4 + i;
        int gl = ci * 64 + lane;
        int row = gl >> 2, cg = gl & 3;
        int sg = cg ^ ((row >> 1) & 3);
        const uint16_t* src = SH + (size_t)(m0 + row) * SWID + p * 32 + sg * 8;
        __builtin_amdgcn_global_load_lds((glb_u32*)src, (lds_u32*)(&smem[buf][0] + ci * 1024), 16, 0, 0);
      }
    } else {
#pragma unroll
      for (int i = 0; i < 2; ++i) {
        int ci = (w - 2) * 2 + i;
        int gl = ci * 64 + lane;
        int row = gl >> 2, cg = gl & 3;
        int sg = cg ^ ((row >> 1) & 3);
        const uint16_t* src = VH + (size_t)(n0 + row) * SWID + p * 32 + sg * 8;
        __builtin_amdgcn_global_load_lds((glb_u32*)src, (lds_u32*)(&smem[buf][8192] + ci * 1024), 16, 0, 0);
      }
    }
  };

  stage(0, 0);
  __syncthreads();
  int fr = lane & 15, fg = lane >> 4;

  for (int p = 0; p < 124; ++p) {
    int cur = p & 1;
    if (p + 1 < 124) stage(cur ^ 1, p + 1);
    short8v a_h[4], b_h[2];
#pragma unroll
    for (int q = 0; q < 4; ++q) {
      int ra = wm * 64 + q * 16 + fr;
      a_h[q] = *(const short8v*)(&smem[cur][0] + ra * 64 + ((fg ^ ((ra >> 1) & 3)) << 4));
    }
#pragma unroll
    for (int s = 0; s < 2; ++s) {
      int rb = wn * 32 + s * 16 + fr;
      b_h[s] = *(const short8v*)(&smem[cur][8192] + rb * 64 + ((fg ^ ((rb >> 1) & 3)) << 4));
    }
#pragma unroll
    for (int mi = 0; mi < 4; ++mi)
#pragma unroll
      for (int ni = 0; ni < 2; ++ni)
        acc[mi][ni] = __builtin_amdgcn_mfma_f32_16x16x32_bf16(a_h[mi], b_h[ni], acc[mi][ni], 0, 0, 0);
    __syncthreads();
  }

#pragma unroll
  for (int mi = 0; mi < 4; ++mi)
#pragma unroll
    for (int ni = 0; ni < 2; ++ni)
#pragma unroll
      for (int r = 0; r < 4; ++r) {
        int m = m0 + wm * 64 + mi * 16 + ((lane >> 4) << 2) + r;
        int n = n0 + wn * 32 + ni * 16 + (lane & 15);
        if (m < MTOT) ft[(size_t)m * NFFT + n] = acc[mi][ni][r] * (0.5f - 0.5f * ct[n]);
      }
}

// ---------------- LayerNorm rows, optional packed out (hi only) ----------------
__global__ __launch_bounds__(256) void ln2_kernel(float* __restrict__ x, const float* __restrict__ g,
                                                  const float* __restrict__ bta,
                                                  uint32_t* __restrict__ PH) {
  int row = blockIdx.x * 4 + (threadIdx.x >> 6);
  int lane = threadIdx.x & 63;
  float* xr = x + (size_t)row * CI;
  int c0 = lane * 8;
  float4 v0 = *(float4*)&xr[c0], v1 = *(float4*)&xr[c0 + 4];
  float s = v0.x + v0.y + v0.z + v0.w + v1.x + v1.y + v1.z + v1.w;
#pragma unroll
  for (int m = 1; m < 64; m <<= 1) s += __shfl_xor(s, m, 64);
  float mean = s * (1.0f / CI);
  float d[8] = {v0.x - mean, v0.y - mean, v0.z - mean, v0.w - mean,
                v1.x - mean, v1.y - mean, v1.z - mean, v1.w - mean};
  float s2 = 0.f;
#pragma unroll
  for (int q = 0; q < 8; ++q) s2 += d[q] * d[q];
#pragma unroll
  for (int m = 1; m < 64; m <<= 1) s2 += __shfl_xor(s2, m, 64);
  float rs = rsqrtf(s2 * (1.0f / CI) + 1e-5f);
  float o[8];
#pragma unroll
  for (int q = 0; q < 8; ++q) o[q] = d[q] * rs * g[c0 + q] + bta[c0 + q];
  float4 w0 = {o[0], o[1], o[2], o[3]}, w1 = {o[4], o[5], o[6], o[7]};
  *(float4*)&xr[c0] = w0; *(float4*)&xr[c0 + 4] = w1;
  if (PH) {
    int base = (row * CI + c0) >> 1;
#pragma unroll
    for (int q = 0; q < 4; ++q)
      PH[base + q] = pack2(o[2 * q], o[2 * q + 1], false);
  }
}

// ---------------- fused dwconv K=7 + LN -> packed (hi only), dual-trunk batched ----------------
__global__ __launch_bounds__(256) void dwln_kernel(const float* __restrict__ xs,
    const float* __restrict__ dws, const float* __restrict__ dbs,
    const float* __restrict__ gs, const float* __restrict__ bts,
    const float* __restrict__ dwf, const float* __restrict__ dbf,
    const float* __restrict__ gf, const float* __restrict__ btf,
    uint32_t* __restrict__ PH) {
  int row = blockIdx.x;
  int half = row >= MTOT;
  const float* dw = half ? dwf : dws;
  const float* db = half ? dbf : dbs;
  const float* g  = half ? gf : gs;
  const float* bt = half ? btf : bts;
  int rb = row - half * MTOT;
  int b = rb / LF, l = rb % LF;
  int rbase = half * MTOT + b * LF;
  int c = threadIdx.x * 2;
  float ax = db[c], ay = db[c + 1];
#pragma unroll
  for (int tau = 0; tau < 7; ++tau) {
    int j = l + tau - 3;
    if (j < 0 || j >= LF) continue;
    float2 xv = *(const float2*)&xs[((size_t)(rbase + j)) * CI + c];
    ax = fmaf(xv.x, dw[c * 7 + tau], ax);
    ay = fmaf(xv.y, dw[(c + 1) * 7 + tau], ay);
  }
  __shared__ float red[4], red2[4];
  float s = ax + ay;
#pragma unroll
  for (int m = 1; m < 64; m <<= 1) s += __shfl_xor(s, m, 64);
  if ((threadIdx.x & 63) == 0) red[threadIdx.x >> 6] = s;
  __syncthreads();
  float mean = (red[0] + red[1] + red[2] + red[3]) * (1.0f / CI);
  float dx = ax - mean, dy = ay - mean;
  float s2 = dx * dx + dy * dy;
#pragma unroll
  for (int m = 1; m < 64; m <<= 1) s2 += __shfl_xor(s2, m, 64);
  if ((threadIdx.x & 63) == 0) red2[threadIdx.x >> 6] = s2;
  __syncthreads();
  float var = (red2[0] + red2[1] + red2[2] + red2[3]) * (1.0f / CI);
  float rs = rsqrtf(var + 1e-5f);
  float vx = dx * rs * g[c] + bt[c];
  float vy = dy * rs * g[c + 1] + bt[c + 1];
  PH[(size_t)row * 256 + threadIdx.x] = pack2(vx, vy, false);
}

// ---------------- amps head ----------------
__global__ __launch_bounds__(256) void amps2_kernel(const float* __restrict__ x, const float* __restrict__ w,
                                                    const float* __restrict__ bias, float* __restrict__ amps) {
  int row = blockIdx.x * 4 + (threadIdx.x >> 6);
  int lane = threadIdx.x & 63;
  const float* xr = x + (size_t)row * CI;
  int c0 = lane * 8;
  float4 v0 = *(const float4*)&xr[c0], v1 = *(const float4*)&xr[c0 + 4];
  float4 w0 = *(const float4*)&w[c0], w1 = *(const float4*)&w[c0 + 4];
  float s = v0.x * w0.x + v0.y * w0.y + v0.z * w0.z + v0.w * w0.w
          + v1.x * w1.x + v1.y * w1.y + v1.z * w1.z + v1.w * w1.w;
#pragma unroll
  for (int m = 1; m < 64; m <<= 1) s += __shfl_xor(s, m, 64);
  if (lane == 0) {
    float a = s + bias[0];
    amps[row] = (a > 0.f ? a : expm1f(a)) + 1.0f;
  }
}

// ---------------- im2col packed (edge pad 3), hi only ----------------
__global__ void im2col_pk(const float* __restrict__ x, uint32_t* __restrict__ PH) {
  int idx = blockIdx.x * 256 + threadIdx.x;
  if (idx >= MTOT * 1792) return;
  int row = idx / 1792, kp = idx % 1792;
  int b = row / LF, l = row % LF;
  float v2[2];
#pragma unroll
  for (int u = 0; u < 2; ++u) {
    int kap = kp * 2 + u;
    int ch = kap / 7, tau = kap % 7;
    int j = l + tau - 3;
    j = j < 0 ? 0 : (j > LF - 1 ? LF - 1 : j);
    v2[u] = x[((size_t)b * LF + j) * CI + ch];
  }
  PH[idx] = pack2(v2[0], v2[1], false);
}

// ---------------- noise*window packed A hi (1664 x 3840); window via ctab ----------------
__global__ void pack_noise(const float* __restrict__ ct, uint32_t* __restrict__ AH) {
  int idx = blockIdx.x * 256 + threadIdx.x;
  if (idx >= MPAD * 1920) return;
  int t = idx / 1920, jp = idx % 1920;
  float v0 = 0.f, v1 = 0.f;
  if (t < MTOT) {
    int b = t / LF, tt = t % LF;
    int j = jp * 2;
    v0 = noiseval(b, tt * 960 + j - 960) * (0.5f - 0.5f * ct[j]);
    v1 = noiseval(b, tt * 960 + j - 959) * (0.5f - 0.5f * ct[j + 1]);
  }
  AH[idx] = pack2(v0, v1, false);
}

// ---------------- twiddle table hi T[k2][j] via cos table ----------------
__global__ void twfill_pk(const float* __restrict__ ct, uint32_t* __restrict__ TH) {
  int idx = blockIdx.x * 256 + threadIdx.x;
  if (idx >= SWID * 1920) return;
  int k2 = idx / 1920, jp = idx % 1920;
  float v2[2] = {0.f, 0.f};
  if (k2 < NK2) {
    int k = k2 >> 1;
    int add = (k2 & 1) * 960;
#pragma unroll
    for (int u = 0; u < 2; ++u) {
      int j = jp * 2 + u;
      int m = (j * k) % NFFT;
      m += add;
      if (m >= NFFT) m -= NFFT;
      v2[u] = ct[m];
    }
  }
  TH[idx] = pack2(v2[0], v2[1], false);
}

// ---------------- harmonic path: fs interp fused into cumsum1; csum holds RAW chunk sums ----------------
__global__ __launch_bounds__(256) void cumsum1(const float* __restrict__ f0, float* __restrict__ fs,
                                               double* __restrict__ csum) {
  int b = blockIdx.y, ch = blockIdx.x;
  int base = ch * 1024;
  double s = 0.0;
  for (int q = 0; q < 4; ++q) {
    int n = base + threadIdx.x * 4 + q;
    if (n < LW) {
      float pos = ((float)n + 0.5f) * (200.0f / 192000.0f) - 0.5f;
      pos = fminf(fmaxf(pos, 0.0f), 199.0f);
      int i0 = (int)pos;
      int i1 = min(i0 + 1, 199);
      float w = pos - (float)i0;
      float fsv = f0[b * LF + i0] * (1.0f - w) + f0[b * LF + i1] * w;
      fs[(size_t)b * LW + n] = fsv;
      s += (double)((3.14159274101257324f * fsv) / 48000.0f);
    }
  }
  __shared__ double sh[256];
  sh[threadIdx.x] = s;
  __syncthreads();
  for (int o2 = 128; o2 > 0; o2 >>= 1) {
    if (threadIdx.x < o2) sh[threadIdx.x] += sh[threadIdx.x + o2];
    __syncthreads();
  }
  if (threadIdx.x == 0) csum[b * NCH + ch] = sh[0];
}

__global__ __launch_bounds__(256) void harm_kernel(
    const float* __restrict__ fs, const double* __restrict__ csum,
    const float* __restrict__ f0, const float* __restrict__ amps,
    float* __restrict__ harm) {
  int b = blockIdx.y, ch = blockIdx.x;
  const float* fsb = fs + (size_t)b * LW;
  int base = ch * 1024;
  int tid = threadIdx.x;
  double p[4]; double s = 0.0;
  int n0 = base + tid * 4;
  for (int q = 0; q < 4; ++q) {
    int n = n0 + q; float sm = 0.f;
    if (n < LW) sm = (3.14159274101257324f * fsb[n]) / 48000.0f;
    s += (double)sm; p[q] = s;
  }
  __shared__ double sh[256];
  sh[tid] = (tid < ch) ? csum[b * NCH + tid] : 0.0;
  __syncthreads();
  for (int o2 = 128; o2 > 0; o2 >>= 1) {
    if (tid < o2) sh[tid] += sh[tid + o2];
    __syncthreads();
  }
  double cbase = sh[0];
  __syncthreads();
  sh[tid] = s; __syncthreads();
  for (int o2 = 1; o2 < 256; o2 <<= 1) {
    double v = (tid >= o2) ? sh[tid - o2] : 0.0;
    __syncthreads();
    sh[tid] += v;
    __syncthreads();
  }
  double excl = cbase + (tid > 0 ? sh[tid - 1] : 0.0);
  const double PID = (double)3.14159274101257324f;
  for (int q = 0; q < 4; ++q) {
    int n = n0 + q; if (n >= LW) break;
    double S = excl + p[q];
    float pixf = (float)fmod(S, PID);
    float fsv = fsb[n];
    float a = rintf(48000.0f / fmaxf(fsv, 20.0f) * 0.5f) * 2.0f + 1.0f;
    float D = (pixf < 1e-8f) ? 1.0f : (sinf(a * pixf) / (a * sinf(pixf)));
    int ui = n / 960;
    float uv = (f0[b * LF + ui] > 20.0f) ? 1.0f : 0.0f;
    float posA = ((float)n + 0.5f) * (200.0f / 192000.0f) - 0.5f;
    posA = fminf(fmaxf(posA, 0.0f), 199.0f);
    int i0 = (int)posA;
    int i1 = min(i0 + 1, 199);
    float w = posA - (float)i0;
    float ampI = amps[b * LF + i0] * (1.0f - w) + amps[b * LF + i1] * w;
    harm[(size_t)b * LW + n] = (D * uv) * ampI;
  }
}

// ---------------- fused OLA + FIR -> per-frame output (plain stores); window via ctab ----------------
__global__ __launch_bounds__(256) void fir5_kernel(const float* __restrict__ ft,
                                                   const float* __restrict__ harm,
                                                   const float* __restrict__ filt,
                                                   const float* __restrict__ ct,
                                                   float* __restrict__ outf) {
  int t = blockIdx.x, b = blockIdx.y;
  __shared__ float frp[3456];
  __shared__ float fl[NWIN];
  int tid = threadIdx.x;
  for (int i = tid; i < 3456; i += 256) frp[i] = 0.f;
  __syncthreads();
  for (int i = tid; i < FRAME; i += 256) {
    int n = t * FRAME + i;
    int p = n + 1920;
    int t0 = (p > 3839) ? ((p - 2880) / 960) : 0;
    int t1 = p / FRAME; if (t1 > 200) t1 = 200;
    float y = 0.f, wn = 0.f;
    for (int tt = t0; tt <= t1; ++tt) {
      int j = p - FRAME * tt;
      float w = 0.5f - 0.5f * ct[j];
      wn += w * w;
      if (tt >= 1) y += ft[((size_t)b * LF + (tt - 1)) * NFFT + j];
    }
    float den = wn > 1e-11f ? wn : 1.0f;
    float dspv = harm[(size_t)b * LW + n] + y / den;
    int x = 1024 + i;
    frp[x + (x >> 3)] = dspv;
  }
  for (int i = tid; i < NWIN; i += 256) fl[i] = filt[((size_t)b * LF + t) * NWIN + i];
  __syncthreads();
  float a[8] = {0.f, 0.f, 0.f, 0.f, 0.f, 0.f, 0.f, 0.f};
  float wbuf[8];
  int base = 9 * tid;
#pragma unroll
  for (int r = 0; r < 8; ++r) wbuf[r] = frp[base + r];
  int nbase = base + 9;
  for (int tau8 = 0; tau8 < 128; ++tau8) {
    int nb = nbase + tau8 * 9;
#pragma unroll
    for (int r = 0; r < 8; ++r) {
      float fv = fl[tau8 * 8 + r];
#pragma unroll
      for (int q = 0; q < 8; ++q)
        a[q] = fmaf(wbuf[(r + q) & 7], fv, a[q]);
      wbuf[r] = frp[nb + r];
    }
  }
#pragma unroll
  for (int q = 0; q < 8; ++q) {
    int i = tid * 8 + q;
    if (i < 1984) outf[((size_t)b * LF + t) * 1984 + i] = a[q];
  }
}

// ---------------- fold (plain stores; overwrites every output element) ----------------
__global__ void fold_kernel(const float* __restrict__ outf, float* __restrict__ out) {
  int idx = blockIdx.x * 256 + threadIdx.x;
  if (idx >= NB * LW) return;
  int b = idx / LW, n = idx % LW;
  int t0 = (n >= 1984) ? ((n - 1024) / 960) : 0;
  int t1 = n / 960; if (t1 > 199) t1 = 199;
  float acc = 0.f;
  for (int t = t0; t <= t1; ++t)
    acc += outf[((size_t)b * LF + t) * 1984 + (n - 960 * t)];
  out[idx] = acc;
}

extern "C" void kernel_launch(void* const* d_in, const int* in_sizes, int n_in,
                              void* d_out, int out_size, void* d_ws, size_t ws_size,
                              hipStream_t stream) {
  const float* content    = (const float*)d_in[0];
  const float* f0         = (const float*)d_in[1];
  const float* energy     = (const float*)d_in[2];
  const float* spk        = (const float*)d_in[3];
  const float* s_in_w     = (const float*)d_in[4];
  const float* s_in_b     = (const float*)d_in[5];
  const float* s_dw_w     = (const float*)d_in[6];
  const float* s_dw_b     = (const float*)d_in[7];
  const float* s_ln       = (const float*)d_in[8];
  const float* s_pw1_w    = (const float*)d_in[9];
  const float* s_pw1_b    = (const float*)d_in[10];
  const float* s_pw2_w    = (const float*)d_in[11];
  const float* s_pw2_b    = (const float*)d_in[12];
  const float* s_out_norm = (const float*)d_in[13];
  const float* f_in_w     = (const float*)d_in[14];
  const float* f_in_b     = (const float*)d_in[15];
  const float* f_dw_w     = (const float*)d_in[16];
  const float* f_dw_b     = (const float*)d_in[17];
  const float* f_ln       = (const float*)d_in[18];
  const float* f_pw1_w    = (const float*)d_in[19];
  const float* f_pw1_b    = (const float*)d_in[20];
  const float* f_pw2_w    = (const float*)d_in[21];
  const float* f_pw2_b    = (const float*)d_in[22];
  const float* f_out_norm = (const float*)d_in[23];
  const float* s_in_norm  = (const float*)d_in[24];
  const float* s_amp_w    = (const float*)d_in[25];
  const float* s_amp_b    = (const float*)d_in[26];
  const float* s_ker_w    = (const float*)d_in[27];
  const float* s_ker_b    = (const float*)d_in[28];
  const float* f_out_w    = (const float*)d_in[29];
  const float* f_out_b    = (const float*)d_in[30];

  // ---- workspace layout (unchanged) ----
  char* W0 = (char*)d_ws;
  double*   CSUM  = (double*)W0;                         // 12,032
  uint32_t* XINPH = (uint32_t*)(W0 + 12032);             // 3,072,000
  float*    XS    = (float*)   (W0 + 6156032);           // 6,553,600 (3200 x 512)
  uint32_t* TPH   = (uint32_t*)(W0 + 12709632);          // 3,276,800 (3200 x 256)
  uint16_t* KERH  = (uint16_t*)(W0 + 19263232);          // 6,147,200
  float*    AMPS  = (float*)   (W0 + 25410432);          // 8,192
  float*    FILT  = (float*)   (W0 + 25418624);          // 6,553,600
  float*    HARM  = (float*)   (W0 + 31972224);          // 6,144,000
  char*     R2    = W0 + 38116224;                       // 26,411,008
  char*     FTR   = W0 + 64527232;                       // 24,576,000
  char*     U     = W0 + 89103232;                       // 25,559,040
  uint32_t* TH32  = (uint32_t*)(W0 + 114662272);         // 30,474,240  (pw2 packs -> T -> V)
  float*    CTAB  = (float*)   (W0 + 175610752);         // 15,360 -> ends 175,626,112
  // overlays
  uint32_t* XSPH = TPH;                                  // (after trunk, TP dead)
  uint32_t* H15PH = (uint32_t*)R2;                       // 9,830,400 (3200 x 768) hi-only
  uint32_t* IMPH = (uint32_t*)R2;                        // 11,468,800 (after H15 dead)
  uint16_t* SH   = (uint16_t*)R2;                        // 13,205,504 (1664 x 3968, after IMP dead)
  float*    OUTF = (float*)R2;                           // 12,697,600 (after SH dead post-invNT)
  float*    FS   = (float*)FTR;                          // 6,144,000
  float*    FT   = (float*)FTR;                          // 24,576,000 (after FS dead)
  // weight-pack blobs (hi only):
  uint32_t* PW1PH_A = (uint32_t*)FTR;                    // layers 0-2 (dead before FS)
  uint32_t* PW1PH_B = (uint32_t*)U;                      // layers 3-5 (dead before ker/fout packs)
  uint32_t* PW2PH = TH32;                                // pw2 all 6 layers (dead before twfill_pk)
  uint32_t* WINPH = (uint32_t*)R2;                       // in-proj pack (dead before H15)
  uint32_t* WPH  = (uint32_t*)U;                         // ker/fout packs, post-trunk
  uint16_t* AH   = (uint16_t*)U;                         // noise A hi (after WP dead)

  (void)in_sizes; (void)n_in; (void)out_size; (void)ws_size;

  ctab_fill<<<dim3(15), 256, 0, stream>>>(CTAB);
  build_xin_pk<<<dim3((MB2 * 240 + 255) / 256), 256, 0, stream>>>(content, f0, energy, spk, XINPH);

  // ---- mega-pack all trunk weights upfront (hi only) ----
  {
    int perset = HID * 256;
    int tot3 = 3 * 2 * perset;
    pack_wN<<<dim3((tot3 + 255) / 256), 256, 0, stream>>>(s_pw1_w, f_pw1_w, (size_t)HID * CI,
        PW1PH_A, HID, CI, 256, perset, tot3);
    pack_wN<<<dim3((tot3 + 255) / 256), 256, 0, stream>>>(s_pw1_w + (size_t)3 * HID * CI,
        f_pw1_w + (size_t)3 * HID * CI, (size_t)HID * CI,
        PW1PH_B, HID, CI, 256, perset, tot3);
    int tot6 = 6 * 2 * perset;
    pack_wN<<<dim3((tot6 + 255) / 256), 256, 0, stream>>>(s_pw2_w, f_pw2_w, (size_t)CI * HID,
        PW2PH, CI, HID, 768, perset, tot6);
  }
  {
    int total = CI * 240;
    pack_w2<<<dim3((2 * total + 255) / 256), 256, 0, stream>>>(s_in_w, f_in_w, WINPH, CI, CIN, 240, total);
  }

  // ---- batched dual-trunk (64x64 tiles, single-bf16) ----
  gemm_bf<<<dim3(8 * 50), 256, 0, stream>>>((uint16_t*)WINPH, (uint16_t*)XINPH,
      s_in_b, f_in_b, nullptr, XS, nullptr, CI, 480, 8, 50, 0, 0, 25, (size_t)512 * 480);
  ln2_kernel<<<dim3(MTOT / 4), 256, 0, stream>>>(XS, s_in_norm, s_in_norm + CI, nullptr);
  for (int i = 0; i < NL; ++i) {
    dwln_kernel<<<dim3(MB2), 256, 0, stream>>>(XS,
        s_dw_w + (size_t)i * CI * 7, s_dw_b + (size_t)i * CI,
        s_ln + (size_t)(i * 2) * CI, s_ln + (size_t)(i * 2 + 1) * CI,
        f_dw_w + (size_t)i * CI * 7, f_dw_b + (size_t)i * CI,
        f_ln + (size_t)(i * 2) * CI, f_ln + (size_t)(i * 2 + 1) * CI,
        TPH);
    const uint16_t* w1h = (i < 3) ? (const uint16_t*)((char*)PW1PH_A + (size_t)i * 3145728)
                                  : (const uint16_t*)((char*)PW1PH_B + (size_t)(i - 3) * 3145728);
    gemm_bf<<<dim3(24 * 50), 256, 0, stream>>>(w1h, (uint16_t*)TPH,
        s_pw1_b + (size_t)i * HID, f_pw1_b + (size_t)i * HID, nullptr,
        nullptr, (uint16_t*)H15PH, HID, 512, 24, 50, 1, 1, 25, (size_t)1536 * 512);
    const uint16_t* w2h = (const uint16_t*)((char*)PW2PH + (size_t)i * 3145728);
    gemm_bf<<<dim3(8 * 50), 256, 0, stream>>>(w2h, (uint16_t*)H15PH,
        s_pw2_b + (size_t)i * CI, f_pw2_b + (size_t)i * CI, XS,
        XS, nullptr, CI, 1536, 8, 50, 0, 0, 25, (size_t)512 * 1536);
  }

  // ---- heads ----
  ln2_kernel<<<dim3(MTOT / 4), 256, 0, stream>>>(XS, s_out_norm, s_out_norm + CI, XSPH);
  amps2_kernel<<<dim3(MTOT / 4), 256, 0, stream>>>(XS, s_amp_w, s_amp_b, AMPS);
  {
    int total = 1984 * 256;
    pack_w<<<dim3((total + 255) / 256), 256, 0, stream>>>(s_ker_w, WPH, NFREQ, CI, 256, total);
  }
  gemm_bf<<<dim3(31 * 25), 256, 0, stream>>>((uint16_t*)WPH, (uint16_t*)XSPH,
      s_ker_b, nullptr, nullptr, nullptr, KERH, NFREQ, 512, 31, 25, 2, 2, 1000, 0);

  ln2_kernel<<<dim3(MTOT / 4), 256, 0, stream>>>(XS + (size_t)MTOT * CI, f_out_norm, f_out_norm + CI, nullptr);
  im2col_pk<<<dim3((MTOT * 1792 + 255) / 256), 256, 0, stream>>>(XS + (size_t)MTOT * CI, IMPH);
  {
    int total = NWIN * 1792;
    pack_w<<<dim3((total + 255) / 256), 256, 0, stream>>>(f_out_w, WPH, NWIN, 3584, 1792, total);
  }
  gemm_bf<<<dim3(16 * 25), 256, 0, stream>>>((uint16_t*)WPH, (uint16_t*)IMPH,
      f_out_b, nullptr, nullptr, FILT, nullptr, NWIN, 3584, 16, 25, 0, 0, 1000, 0);

  // ---- harmonic source (FS lives in FT region, dead before inv) ----
  cumsum1<<<dim3(NCH, NB), 256, 0, stream>>>(f0, FS, CSUM);
  harm_kernel<<<dim3(NCH, NB), 256, 0, stream>>>(FS, CSUM, f0, AMPS, HARM);

  // ---- filtered noise: fwd (T table) then inv (V table overwrites T), single-bf16, 128x64 tiles ----
  pack_noise<<<dim3((MPAD * 1920 + 255) / 256), 256, 0, stream>>>(CTAB, (uint32_t*)AH);
  twfill_pk<<<dim3((SWID * 1920 + 255) / 256), 256, 0, stream>>>(CTAB, TH32);
  gemm_fwd128<<<dim3(13 * 62), 256, 0, stream>>>((uint16_t*)AH, (uint16_t*)TH32, KERH, SH);
  twfill_v<<<dim3((NFFT * (SWID / 2) + 255) / 256), 256, 0, stream>>>(CTAB, TH32);
  gemm_invNT<<<dim3(60 * 13), 256, 0, stream>>>(SH, (uint16_t*)TH32, CTAB, FT);

  // ---- fused OLA + FIR (plain stores) + fold ----
  fir5_kernel<<<dim3(LF, NB), 256, 0, stream>>>(FT, HARM, FILT, CTAB, OUTF);
  fold_kernel<<<dim3((NB * LW + 255) / 256), 256, 0, stream>>>(OUTF, (float*)d_out);
}

// Round 21
// 871.928 us; speedup vs baseline: 1.0799x; 1.0799x over previous
//
#include <hip/hip_runtime.h>
#include <hip/hip_bf16.h>
#include <math.h>
#include <stdint.h>

#define FRAME 960
#define NFFT  3840
#define NWIN  1024
#define NFREQ 1921
#define NB    8
#define LF    200
#define LW    192000
#define CIN   450
#define CI    512
#define HID   1536
#define NL    6
#define NCH   188
#define NK2   3842
#define MTOT  1600
#define MB2   3200   // both trunks batched
#define SWID  3968   // padded spec width
#define MPAD  1664   // padded frame rows for DFT

typedef __attribute__((ext_vector_type(8))) short short8v;
typedef __attribute__((ext_vector_type(4))) float f32x4;
typedef __attribute__((address_space(3))) uint32_t lds_u32;
typedef const __attribute__((address_space(1))) uint32_t glb_u32;

// ---------------- threefry (JAX partitionable) ----------------
__device__ __forceinline__ uint32_t rotl32(uint32_t v, int r) { return (v << r) | (v >> (32 - r)); }
__device__ __forceinline__ void threefry2x32(uint32_t k0, uint32_t k1, uint32_t& x0, uint32_t& x1) {
  uint32_t ks2 = k0 ^ k1 ^ 0x1BD11BDAu;
  x0 += k0; x1 += k1;
#define TFR(r) { x0 += x1; x1 = rotl32(x1, r); x1 ^= x0; }
  TFR(13) TFR(15) TFR(26) TFR(6)  x0 += k1;  x1 += ks2 + 1u;
  TFR(17) TFR(29) TFR(16) TFR(24) x0 += ks2; x1 += k0 + 2u;
  TFR(13) TFR(15) TFR(26) TFR(6)  x0 += k0;  x1 += k1 + 3u;
  TFR(17) TFR(29) TFR(16) TFR(24) x0 += k1;  x1 += ks2 + 4u;
  TFR(13) TFR(15) TFR(26) TFR(6)  x0 += ks2; x1 += k0 + 5u;
#undef TFR
}
__device__ __forceinline__ float noiseval(int b, int m) {
  if (m < 0) m = -m;
  if (m >= LW) m = 2 * LW - 2 - m;
  uint32_t x0 = 0u, x1 = (uint32_t)(b * LW + m);
  threefry2x32(0u, 123u, x0, x1);
  uint32_t bits = x0 ^ x1;
  return __uint_as_float((bits >> 9) | 0x3f800000u) - 1.0f;
}
__device__ __forceinline__ float winf(int j) {
  return 0.5f - 0.5f * cosf((6.283185307179586f * (float)j) / 3840.0f);
}
__device__ __forceinline__ unsigned short f2bf(float v) {
  uint32_t b = __float_as_uint(v);
  return (unsigned short)((b + 0x7FFFu + ((b >> 16) & 1u)) >> 16);
}
__device__ __forceinline__ float bf2f(unsigned short h) {
  return __uint_as_float(((uint32_t)h) << 16);
}
__device__ __forceinline__ uint32_t pack2(float a, float b, bool lo) {
  unsigned short ha = f2bf(a), hb = f2bf(b);
  if (!lo) return (uint32_t)ha | ((uint32_t)hb << 16);
  return (uint32_t)f2bf(a - bf2f(ha)) | ((uint32_t)f2bf(b - bf2f(hb)) << 16);
}
__device__ __forceinline__ int xcd_remap(int lin, int nwg) {
  int q = nwg >> 3, r = nwg & 7;
  int xcd = lin & 7, base = lin >> 3;
  int start = (xcd < r) ? xcd * (q + 1) : r * (q + 1) + (xcd - r) * q;
  return start + base;
}

// ---------------- cos table (3840 f32), bit-matching winf's cos argument ----------------
__global__ void ctab_fill(float* __restrict__ ct) {
  int j = blockIdx.x * 256 + threadIdx.x;
  if (j < NFFT) ct[j] = cosf((6.283185307179586f * (float)j) / 3840.0f);
}

// ---------------- xin packed (hi only), duplicated for both trunks ----------------
__global__ void build_xin_pk(const float* __restrict__ content, const float* __restrict__ f0,
                             const float* __restrict__ energy, const float* __restrict__ spk,
                             uint32_t* __restrict__ PH) {
  int idx = blockIdx.x * 256 + threadIdx.x;
  if (idx >= MB2 * 240) return;
  int row = idx / 240, cp = idx % 240;
  int rb = row % MTOT;
  int b = rb / LF, l = rb % LF;
  float v2[2];
#pragma unroll
  for (int u = 0; u < 2; ++u) {
    int c = cp * 2 + u;
    float v = 0.f;
    if (c < 192)       v = content[((size_t)b * 192 + c) * LF + l];
    else if (c < 448)  v = spk[b * 256 + (c - 192)];
    else if (c == 448) v = logf(fmaxf(f0[b * LF + l], 0.0f) + 1e-6f);
    else if (c == 449) v = energy[b * LF + l];
    v2[u] = v;
  }
  PH[idx] = pack2(v2[0], v2[1], false);
}

// ---------------- weight pack (single set, hi only) ----------------
__global__ void pack_w(const float* __restrict__ W, uint32_t* __restrict__ PH,
                       int M, int K, int Kp2, int total) {
  int idx = blockIdx.x * 256 + threadIdx.x;
  if (idx >= total) return;
  int m = idx / Kp2, kp = idx % Kp2;
  int k = kp * 2;
  float v0 = (m < M && k < K) ? W[(size_t)m * K + k] : 0.f;
  float v1 = (m < M && (k + 1) < K) ? W[(size_t)m * K + k + 1] : 0.f;
  PH[idx] = pack2(v0, v1, false);
}

// ---------------- weight pack (dual set, one dispatch, hi only) ----------------
__global__ void pack_w2(const float* __restrict__ Ws, const float* __restrict__ Wf,
                        uint32_t* __restrict__ PH, int M, int K, int Kp2, int total) {
  int idx = blockIdx.x * 256 + threadIdx.x;
  if (idx >= 2 * total) return;
  int half = idx >= total;
  const float* W = half ? Wf : Ws;
  int t = idx - half * total;
  int m = t / Kp2, kp = t % Kp2;
  int k = kp * 2;
  float v0 = (m < M && k < K) ? W[(size_t)m * K + k] : 0.f;
  float v1 = (m < M && (k + 1) < K) ? W[(size_t)m * K + k + 1] : 0.f;
  PH[idx] = pack2(v0, v1, false);
}

// ---------------- weight pack (dual set, N layers, one dispatch, hi only) ----------------
__global__ void pack_wN(const float* __restrict__ Ws, const float* __restrict__ Wf, size_t lstride,
                        uint32_t* __restrict__ PH, int M, int K, int Kp2, int perset, int total) {
  int idx = blockIdx.x * 256 + threadIdx.x;
  if (idx >= total) return;
  int l = idx / (2 * perset);
  int r = idx - l * 2 * perset;
  int half = r >= perset;
  const float* W = (half ? Wf : Ws) + (size_t)l * lstride;
  int t = r - half * perset;
  int m = t / Kp2, kp = t % Kp2;
  int k = kp * 2;
  float v0 = (m < M && k < K) ? W[(size_t)m * K + k] : 0.f;
  float v1 = (m < M && (k + 1) < K) ? W[(size_t)m * K + k + 1] : 0.f;
  PH[idx] = pack2(v0, v1, false);
}

// ---------------- single-bf16 NT GEMM, 64x64 tile, dual-weight-set batched ----------------
__global__ __launch_bounds__(256) void gemm_bf(
    const uint16_t* __restrict__ WH, const uint16_t* __restrict__ XH,
    const float* __restrict__ bias, const float* __restrict__ bias2,
    const float* __restrict__ res,
    float* __restrict__ outF, uint16_t* __restrict__ outH,
    int M, int Kp, int mtiles, int ntiles, int mode, int act, int nsp, size_t woff)
{
  __shared__ __align__(16) char smem[2][2][4096];
  int nwg = mtiles * ntiles;
  int wg = xcd_remap(blockIdx.x, nwg);
  int mtile = wg / ntiles, ntile = wg % ntiles;
  int m0 = mtile * 64, n0 = ntile * 64;
  int tid = threadIdx.x;
  int lane = tid & 63, w = tid >> 6;
  int wm = w >> 1, wn = w & 1;
  int rowg = Kp >> 3;
  int phases = Kp >> 5;

  int opsel = w >> 1, whalf = w & 1;
  const uint16_t* gb = (opsel == 0) ? WH : XH;
  if (opsel == 0 && ntile >= nsp) gb += woff;
  int row0 = (opsel == 0) ? m0 : n0;
  f32x4 acc[2][2];
#pragma unroll
  for (int i = 0; i < 2; ++i)
#pragma unroll
    for (int j = 0; j < 2; ++j) acc[i][j] = (f32x4){0.f, 0.f, 0.f, 0.f};

  auto stage = [&](int buf, int p) {
    int kg0 = p * 4;
#pragma unroll
    for (int c = 0; c < 2; ++c) {
      int i = whalf * 2 + c;
      int r = i * 16 + (lane >> 2);
      int scg = lane & 3;
      int sgsel = scg ^ (((lane >> 2) >> 1) & 3);
      const uint16_t* src = gb + (size_t)(row0 + r) * rowg * 8 + (size_t)(kg0 + sgsel) * 8;
      __builtin_amdgcn_global_load_lds((glb_u32*)src, (lds_u32*)(&smem[buf][opsel][0] + i * 1024), 16, 0, 0);
    }
  };

  stage(0, 0);
  __syncthreads();
  int fr = lane & 15, fg = lane >> 4;
  int fsw = ((fr >> 1) & 3);
  int aoff0 = (wm * 32 + fr) * 64 + (fg ^ fsw) * 16;
  int aoff1 = (wm * 32 + 16 + fr) * 64 + (fg ^ fsw) * 16;
  int boff0 = (wn * 32 + fr) * 64 + (fg ^ fsw) * 16;
  int boff1 = (wn * 32 + 16 + fr) * 64 + (fg ^ fsw) * 16;

  for (int p = 0; p < phases; ++p) {
    int cur = p & 1;
    if (p + 1 < phases) stage(cur ^ 1, p + 1);
    short8v ah0 = *(const short8v*)(&smem[cur][0][0] + aoff0);
    short8v ah1 = *(const short8v*)(&smem[cur][0][0] + aoff1);
    short8v bh0 = *(const short8v*)(&smem[cur][1][0] + boff0);
    short8v bh1 = *(const short8v*)(&smem[cur][1][0] + boff1);
    acc[0][0] = __builtin_amdgcn_mfma_f32_16x16x32_bf16(ah0, bh0, acc[0][0], 0, 0, 0);
    acc[0][1] = __builtin_amdgcn_mfma_f32_16x16x32_bf16(ah0, bh1, acc[0][1], 0, 0, 0);
    acc[1][0] = __builtin_amdgcn_mfma_f32_16x16x32_bf16(ah1, bh0, acc[1][0], 0, 0, 0);
    acc[1][1] = __builtin_amdgcn_mfma_f32_16x16x32_bf16(ah1, bh1, acc[1][1], 0, 0, 0);
    __syncthreads();
  }

#pragma unroll
  for (int mi = 0; mi < 2; ++mi)
#pragma unroll
    for (int ni = 0; ni < 2; ++ni)
#pragma unroll
      for (int r = 0; r < 4; ++r) {
        int m = m0 + wm * 32 + mi * 16 + ((lane >> 4) << 2) + r;
        int n = n0 + wn * 32 + ni * 16 + (lane & 15);
        if (m >= M) continue;
        float v = acc[mi][ni][r];
        if (bias) v += (bias2 && n >= nsp * 64) ? bias2[m] : bias[m];
        if (act == 1)      v = 0.5f * v * (1.0f + erff(v * 0.7071067811865475f));
        else if (act == 2) v = (v > 0.f ? v : expm1f(v)) + 1.0f;
        if (mode == 0) {
          if (res) v += res[(size_t)n * M + m];
          outF[(size_t)n * M + m] = v;
        } else if (mode == 1) {
          outH[(size_t)n * M + m] = f2bf(v);
        } else {  // 2: KER bf16 (NFREQ row stride)
          outH[(size_t)n * NFREQ + m] = f2bf(v);
        }
      }
}

// ---------------- fwd DFT GEMM: 128x128 tile, 512 threads (8 waves, 2x4), single-bf16 ----------------
__global__ __launch_bounds__(512) void gemm_fwd128(
    const uint16_t* __restrict__ AH, const uint16_t* __restrict__ TH,
    const uint16_t* __restrict__ KERH, uint16_t* __restrict__ SH)
{
  __shared__ __align__(16) char smem[2][2][8192];
  int wg = xcd_remap(blockIdx.x, 13 * 31);
  int ntile = wg / 13, mtile = wg % 13;   // m-inner: T-tile L2-resident
  int m0 = mtile * 128, n0 = ntile * 128;
  int tid = threadIdx.x;
  int lane = tid & 63, w = tid >> 6;      // 8 waves
  int wm = w >> 2, wn = w & 3;            // 2x4: each wave owns 64x32
  f32x4 acc[4][2];
#pragma unroll
  for (int i = 0; i < 4; ++i)
#pragma unroll
    for (int j = 0; j < 2; ++j) acc[i][j] = (f32x4){0.f, 0.f, 0.f, 0.f};

  auto stage = [&](int buf, int p) {
#pragma unroll
    for (int c = 0; c < 2; ++c) {
      int ci = w * 2 + c;                 // 16 chunks: 0-7 A, 8-15 B
      int opsel = ci >> 3;
      int cc = ci & 7;
      int gl = cc * 64 + lane;
      int row = gl >> 2, cg = gl & 3;
      int sg = cg ^ ((row >> 1) & 3);
      const uint16_t* src = (opsel ? TH + (size_t)(n0 + row) * 3840 : AH + (size_t)(m0 + row) * 3840)
                            + p * 32 + sg * 8;
      __builtin_amdgcn_global_load_lds((glb_u32*)src, (lds_u32*)(&smem[buf][opsel][0] + cc * 1024), 16, 0, 0);
    }
  };

  stage(0, 0);
  __syncthreads();
  int fr = lane & 15, fg = lane >> 4;

  for (int p = 0; p < 120; ++p) {
    int cur = p & 1;
    if (p + 1 < 120) stage(cur ^ 1, p + 1);
    short8v a_h[4], b_h[2];
#pragma unroll
    for (int q = 0; q < 4; ++q) {
      int ra = wm * 64 + q * 16 + fr;
      a_h[q] = *(const short8v*)(&smem[cur][0][0] + ra * 64 + ((fg ^ ((ra >> 1) & 3)) << 4));
    }
#pragma unroll
    for (int s = 0; s < 2; ++s) {
      int rb = wn * 32 + s * 16 + fr;
      b_h[s] = *(const short8v*)(&smem[cur][1][0] + rb * 64 + ((fg ^ ((rb >> 1) & 3)) << 4));
    }
#pragma unroll
    for (int mi = 0; mi < 4; ++mi)
#pragma unroll
      for (int ni = 0; ni < 2; ++ni)
        acc[mi][ni] = __builtin_amdgcn_mfma_f32_16x16x32_bf16(a_h[mi], b_h[ni], acc[mi][ni], 0, 0, 0);
    __syncthreads();
  }

#pragma unroll
  for (int mi = 0; mi < 4; ++mi)
#pragma unroll
    for (int ni = 0; ni < 2; ++ni)
#pragma unroll
      for (int r = 0; r < 4; ++r) {
        int m = m0 + wm * 64 + mi * 16 + ((lane >> 4) << 2) + r;
        int n = n0 + wn * 32 + ni * 16 + (lane & 15);
        if (m < MTOT) {
          float o = 0.f;
          if (n < NK2) {
            int k = n >> 1;
            float kv = bf2f(KERH[(size_t)m * NFREQ + k]);
            bool edge = (k == 0) || (k == 1920);
            float mult = edge ? (1.0f / NFFT) : (2.0f / NFFT);
            o = acc[mi][ni][r] * kv * mult;
            if ((n & 1) && edge) o = 0.f;
          }
          SH[(size_t)m * SWID + n] = f2bf(o);
        }
      }
}

// ---------------- transposed twiddle V[j][k2] via cos table (hi only; overwrites T after fwd) ----------------
__global__ void twfill_v(const float* __restrict__ ct, uint32_t* __restrict__ VH) {
  int idx = blockIdx.x * 256 + threadIdx.x;
  if (idx >= NFFT * (SWID / 2)) return;
  int j = idx / (SWID / 2), kp = idx % (SWID / 2);
  float v2[2] = {0.f, 0.f};
#pragma unroll
  for (int u = 0; u < 2; ++u) {
    int k2 = kp * 2 + u;
    if (k2 < NK2) {
      int k = k2 >> 1;
      int m = (j * k) % NFFT;
      m += (k2 & 1) * 960;               // -sin(x) = cos(x + pi/2)
      if (m >= NFFT) m -= NFFT;
      v2[u] = ct[m];
    }
  }
  VH[idx] = pack2(v2[0], v2[1], false);
}

// ---------------- inverse DFT as pure NT GEMM: 128x128 tile, 512 threads; window via ctab ----------------
__global__ __launch_bounds__(512) void gemm_invNT(
    const uint16_t* __restrict__ SH, const uint16_t* __restrict__ VH,
    const float* __restrict__ ct, float* __restrict__ ft)
{
  __shared__ __align__(16) char smem[2][2][8192];
  int wg = xcd_remap(blockIdx.x, 30 * 13);
  int ntile = wg / 13, mtile = wg % 13;   // m-inner: V-tile L2-resident
  int m0 = mtile * 128, n0 = ntile * 128;
  int tid = threadIdx.x;
  int lane = tid & 63, w = tid >> 6;
  int wm = w >> 2, wn = w & 3;
  f32x4 acc[4][2];
#pragma unroll
  for (int i = 0; i < 4; ++i)
#pragma unroll
    for (int j = 0; j < 2; ++j) acc[i][j] = (f32x4){0.f, 0.f, 0.f, 0.f};

  auto stage = [&](int buf, int p) {
#pragma unroll
    for (int c = 0; c < 2; ++c) {
      int ci = w * 2 + c;
      int opsel = ci >> 3;
      int cc = ci & 7;
      int gl = cc * 64 + lane;
      int row = gl >> 2, cg = gl & 3;
      int sg = cg ^ ((row >> 1) & 3);
      const uint16_t* src = (opsel ? VH + (size_t)(n0 + row) * SWID : SH + (size_t)(m0 + row) * SWID)
                            + p * 32 + sg * 8;
      __builtin_amdgcn_global_load_lds((glb_u32*)src, (lds_u32*)(&smem[buf][opsel][0] + cc * 1024), 16, 0, 0);
    }
  };

  stage(0, 0);
  __syncthreads();
  int fr = lane & 15, fg = lane >> 4;

  for (int p = 0; p < 124; ++p) {
    int cur = p & 1;
    if (p + 1 < 124) stage(cur ^ 1, p + 1);
    short8v a_h[4], b_h[2];
#pragma unroll
    for (int q = 0; q < 4; ++q) {
      int ra = wm * 64 + q * 16 + fr;
      a_h[q] = *(const short8v*)(&smem[cur][0][0] + ra * 64 + ((fg ^ ((ra >> 1) & 3)) << 4));
    }
#pragma unroll
    for (int s = 0; s < 2; ++s) {
      int rb = wn * 32 + s * 16 + fr;
      b_h[s] = *(const short8v*)(&smem[cur][1][0] + rb * 64 + ((fg ^ ((rb >> 1) & 3)) << 4));
    }
#pragma unroll
    for (int mi = 0; mi < 4; ++mi)
#pragma unroll
      for (int ni = 0; ni < 2; ++ni)
        acc[mi][ni] = __builtin_amdgcn_mfma_f32_16x16x32_bf16(a_h[mi], b_h[ni], acc[mi][ni], 0, 0, 0);
    __syncthreads();
  }

#pragma unroll
  for (int mi = 0; mi < 4; ++mi)
#pragma unroll
    for (int ni = 0; ni < 2; ++ni)
#pragma unroll
      for (int r = 0; r < 4; ++r) {
        int m = m0 + wm * 64 + mi * 16 + ((lane >> 4) << 2) + r;
        int n = n0 + wn * 32 + ni * 16 + (lane & 15);
        if (m < MTOT) ft[(size_t)m * NFFT + n] = acc[mi][ni][r] * (0.5f - 0.5f * ct[n]);
      }
}

// ---------------- LayerNorm rows, optional packed out (hi only) ----------------
__global__ __launch_bounds__(256) void ln2_kernel(float* __restrict__ x, const float* __restrict__ g,
                                                  const float* __restrict__ bta,
                                                  uint32_t* __restrict__ PH) {
  int row = blockIdx.x * 4 + (threadIdx.x >> 6);
  int lane = threadIdx.x & 63;
  float* xr = x + (size_t)row * CI;
  int c0 = lane * 8;
  float4 v0 = *(float4*)&xr[c0], v1 = *(float4*)&xr[c0 + 4];
  float s = v0.x + v0.y + v0.z + v0.w + v1.x + v1.y + v1.z + v1.w;
#pragma unroll
  for (int m = 1; m < 64; m <<= 1) s += __shfl_xor(s, m, 64);
  float mean = s * (1.0f / CI);
  float d[8] = {v0.x - mean, v0.y - mean, v0.z - mean, v0.w - mean,
                v1.x - mean, v1.y - mean, v1.z - mean, v1.w - mean};
  float s2 = 0.f;
#pragma unroll
  for (int q = 0; q < 8; ++q) s2 += d[q] * d[q];
#pragma unroll
  for (int m = 1; m < 64; m <<= 1) s2 += __shfl_xor(s2, m, 64);
  float rs = rsqrtf(s2 * (1.0f / CI) + 1e-5f);
  float o[8];
#pragma unroll
  for (int q = 0; q < 8; ++q) o[q] = d[q] * rs * g[c0 + q] + bta[c0 + q];
  float4 w0 = {o[0], o[1], o[2], o[3]}, w1 = {o[4], o[5], o[6], o[7]};
  *(float4*)&xr[c0] = w0; *(float4*)&xr[c0 + 4] = w1;
  if (PH) {
    int base = (row * CI + c0) >> 1;
#pragma unroll
    for (int q = 0; q < 4; ++q)
      PH[base + q] = pack2(o[2 * q], o[2 * q + 1], false);
  }
}

// ---------------- fused dwconv K=7 + LN -> packed (hi only), dual-trunk batched ----------------
__global__ __launch_bounds__(256) void dwln_kernel(const float* __restrict__ xs,
    const float* __restrict__ dws, const float* __restrict__ dbs,
    const float* __restrict__ gs, const float* __restrict__ bts,
    const float* __restrict__ dwf, const float* __restrict__ dbf,
    const float* __restrict__ gf, const float* __restrict__ btf,
    uint32_t* __restrict__ PH) {
  int row = blockIdx.x;
  int half = row >= MTOT;
  const float* dw = half ? dwf : dws;
  const float* db = half ? dbf : dbs;
  const float* g  = half ? gf : gs;
  const float* bt = half ? btf : bts;
  int rb = row - half * MTOT;
  int b = rb / LF, l = rb % LF;
  int rbase = half * MTOT + b * LF;
  int c = threadIdx.x * 2;
  float ax = db[c], ay = db[c + 1];
#pragma unroll
  for (int tau = 0; tau < 7; ++tau) {
    int j = l + tau - 3;
    if (j < 0 || j >= LF) continue;
    float2 xv = *(const float2*)&xs[((size_t)(rbase + j)) * CI + c];
    ax = fmaf(xv.x, dw[c * 7 + tau], ax);
    ay = fmaf(xv.y, dw[(c + 1) * 7 + tau], ay);
  }
  __shared__ float red[4], red2[4];
  float s = ax + ay;
#pragma unroll
  for (int m = 1; m < 64; m <<= 1) s += __shfl_xor(s, m, 64);
  if ((threadIdx.x & 63) == 0) red[threadIdx.x >> 6] = s;
  __syncthreads();
  float mean = (red[0] + red[1] + red[2] + red[3]) * (1.0f / CI);
  float dx = ax - mean, dy = ay - mean;
  float s2 = dx * dx + dy * dy;
#pragma unroll
  for (int m = 1; m < 64; m <<= 1) s2 += __shfl_xor(s2, m, 64);
  if ((threadIdx.x & 63) == 0) red2[threadIdx.x >> 6] = s2;
  __syncthreads();
  float var = (red2[0] + red2[1] + red2[2] + red2[3]) * (1.0f / CI);
  float rs = rsqrtf(var + 1e-5f);
  float vx = dx * rs * g[c] + bt[c];
  float vy = dy * rs * g[c + 1] + bt[c + 1];
  PH[(size_t)row * 256 + threadIdx.x] = pack2(vx, vy, false);
}

// ---------------- amps head ----------------
__global__ __launch_bounds__(256) void amps2_kernel(const float* __restrict__ x, const float* __restrict__ w,
                                                    const float* __restrict__ bias, float* __restrict__ amps) {
  int row = blockIdx.x * 4 + (threadIdx.x >> 6);
  int lane = threadIdx.x & 63;
  const float* xr = x + (size_t)row * CI;
  int c0 = lane * 8;
  float4 v0 = *(const float4*)&xr[c0], v1 = *(const float4*)&xr[c0 + 4];
  float4 w0 = *(const float4*)&w[c0], w1 = *(const float4*)&w[c0 + 4];
  float s = v0.x * w0.x + v0.y * w0.y + v0.z * w0.z + v0.w * w0.w
          + v1.x * w1.x + v1.y * w1.y + v1.z * w1.z + v1.w * w1.w;
#pragma unroll
  for (int m = 1; m < 64; m <<= 1) s += __shfl_xor(s, m, 64);
  if (lane == 0) {
    float a = s + bias[0];
    amps[row] = (a > 0.f ? a : expm1f(a)) + 1.0f;
  }
}

// ---------------- im2col packed (edge pad 3), hi only ----------------
__global__ void im2col_pk(const float* __restrict__ x, uint32_t* __restrict__ PH) {
  int idx = blockIdx.x * 256 + threadIdx.x;
  if (idx >= MTOT * 1792) return;
  int row = idx / 1792, kp = idx % 1792;
  int b = row / LF, l = row % LF;
  float v2[2];
#pragma unroll
  for (int u = 0; u < 2; ++u) {
    int kap = kp * 2 + u;
    int ch = kap / 7, tau = kap % 7;
    int j = l + tau - 3;
    j = j < 0 ? 0 : (j > LF - 1 ? LF - 1 : j);
    v2[u] = x[((size_t)b * LF + j) * CI + ch];
  }
  PH[idx] = pack2(v2[0], v2[1], false);
}

// ---------------- noise*window packed A hi (1664 x 3840); window via ctab ----------------
__global__ void pack_noise(const float* __restrict__ ct, uint32_t* __restrict__ AH) {
  int idx = blockIdx.x * 256 + threadIdx.x;
  if (idx >= MPAD * 1920) return;
  int t = idx / 1920, jp = idx % 1920;
  float v0 = 0.f, v1 = 0.f;
  if (t < MTOT) {
    int b = t / LF, tt = t % LF;
    int j = jp * 2;
    v0 = noiseval(b, tt * 960 + j - 960) * (0.5f - 0.5f * ct[j]);
    v1 = noiseval(b, tt * 960 + j - 959) * (0.5f - 0.5f * ct[j + 1]);
  }
  AH[idx] = pack2(v0, v1, false);
}

// ---------------- twiddle table hi T[k2][j] via cos table ----------------
__global__ void twfill_pk(const float* __restrict__ ct, uint32_t* __restrict__ TH) {
  int idx = blockIdx.x * 256 + threadIdx.x;
  if (idx >= SWID * 1920) return;
  int k2 = idx / 1920, jp = idx % 1920;
  float v2[2] = {0.f, 0.f};
  if (k2 < NK2) {
    int k = k2 >> 1;
    int add = (k2 & 1) * 960;
#pragma unroll
    for (int u = 0; u < 2; ++u) {
      int j = jp * 2 + u;
      int m = (j * k) % NFFT;
      m += add;
      if (m >= NFFT) m -= NFFT;
      v2[u] = ct[m];
    }
  }
  TH[idx] = pack2(v2[0], v2[1], false);
}

// ---------------- harmonic path: fs interp fused into cumsum1; csum holds RAW chunk sums ----------------
__global__ __launch_bounds__(256) void cumsum1(const float* __restrict__ f0, float* __restrict__ fs,
                                               double* __restrict__ csum) {
  int b = blockIdx.y, ch = blockIdx.x;
  int base = ch * 1024;
  double s = 0.0;
  for (int q = 0; q < 4; ++q) {
    int n = base + threadIdx.x * 4 + q;
    if (n < LW) {
      float pos = ((float)n + 0.5f) * (200.0f / 192000.0f) - 0.5f;
      pos = fminf(fmaxf(pos, 0.0f), 199.0f);
      int i0 = (int)pos;
      int i1 = min(i0 + 1, 199);
      float w = pos - (float)i0;
      float fsv = f0[b * LF + i0] * (1.0f - w) + f0[b * LF + i1] * w;
      fs[(size_t)b * LW + n] = fsv;
      s += (double)((3.14159274101257324f * fsv) / 48000.0f);
    }
  }
  __shared__ double sh[256];
  sh[threadIdx.x] = s;
  __syncthreads();
  for (int o2 = 128; o2 > 0; o2 >>= 1) {
    if (threadIdx.x < o2) sh[threadIdx.x] += sh[threadIdx.x + o2];
    __syncthreads();
  }
  if (threadIdx.x == 0) csum[b * NCH + ch] = sh[0];
}

__global__ __launch_bounds__(256) void harm_kernel(
    const float* __restrict__ fs, const double* __restrict__ csum,
    const float* __restrict__ f0, const float* __restrict__ amps,
    float* __restrict__ harm) {
  int b = blockIdx.y, ch = blockIdx.x;
  const float* fsb = fs + (size_t)b * LW;
  int base = ch * 1024;
  int tid = threadIdx.x;
  double p[4]; double s = 0.0;
  int n0 = base + tid * 4;
  for (int q = 0; q < 4; ++q) {
    int n = n0 + q; float sm = 0.f;
    if (n < LW) sm = (3.14159274101257324f * fsb[n]) / 48000.0f;
    s += (double)sm; p[q] = s;
  }
  __shared__ double sh[256];
  sh[tid] = (tid < ch) ? csum[b * NCH + tid] : 0.0;
  __syncthreads();
  for (int o2 = 128; o2 > 0; o2 >>= 1) {
    if (tid < o2) sh[tid] += sh[tid + o2];
    __syncthreads();
  }
  double cbase = sh[0];
  __syncthreads();
  sh[tid] = s; __syncthreads();
  for (int o2 = 1; o2 < 256; o2 <<= 1) {
    double v = (tid >= o2) ? sh[tid - o2] : 0.0;
    __syncthreads();
    sh[tid] += v;
    __syncthreads();
  }
  double excl = cbase + (tid > 0 ? sh[tid - 1] : 0.0);
  const double PID = (double)3.14159274101257324f;
  for (int q = 0; q < 4; ++q) {
    int n = n0 + q; if (n >= LW) break;
    double S = excl + p[q];
    float pixf = (float)fmod(S, PID);
    float fsv = fsb[n];
    float a = rintf(48000.0f / fmaxf(fsv, 20.0f) * 0.5f) * 2.0f + 1.0f;
    float D = (pixf < 1e-8f) ? 1.0f : (sinf(a * pixf) / (a * sinf(pixf)));
    int ui = n / 960;
    float uv = (f0[b * LF + ui] > 20.0f) ? 1.0f : 0.0f;
    float posA = ((float)n + 0.5f) * (200.0f / 192000.0f) - 0.5f;
    posA = fminf(fmaxf(posA, 0.0f), 199.0f);
    int i0 = (int)posA;
    int i1 = min(i0 + 1, 199);
    float w = posA - (float)i0;
    float ampI = amps[b * LF + i0] * (1.0f - w) + amps[b * LF + i1] * w;
    harm[(size_t)b * LW + n] = (D * uv) * ampI;
  }
}

// ---------------- fused OLA + FIR -> per-frame output (plain stores); window via ctab ----------------
__global__ __launch_bounds__(256) void fir5_kernel(const float* __restrict__ ft,
                                                   const float* __restrict__ harm,
                                                   const float* __restrict__ filt,
                                                   const float* __restrict__ ct,
                                                   float* __restrict__ outf) {
  int t = blockIdx.x, b = blockIdx.y;
  __shared__ float frp[3456];
  __shared__ float fl[NWIN];
  int tid = threadIdx.x;
  for (int i = tid; i < 3456; i += 256) frp[i] = 0.f;
  __syncthreads();
  for (int i = tid; i < FRAME; i += 256) {
    int n = t * FRAME + i;
    int p = n + 1920;
    int t0 = (p > 3839) ? ((p - 2880) / 960) : 0;
    int t1 = p / FRAME; if (t1 > 200) t1 = 200;
    float y = 0.f, wn = 0.f;
    for (int tt = t0; tt <= t1; ++tt) {
      int j = p - FRAME * tt;
      float w = 0.5f - 0.5f * ct[j];
      wn += w * w;
      if (tt >= 1) y += ft[((size_t)b * LF + (tt - 1)) * NFFT + j];
    }
    float den = wn > 1e-11f ? wn : 1.0f;
    float dspv = harm[(size_t)b * LW + n] + y / den;
    int x = 1024 + i;
    frp[x + (x >> 3)] = dspv;
  }
  for (int i = tid; i < NWIN; i += 256) fl[i] = filt[((size_t)b * LF + t) * NWIN + i];
  __syncthreads();
  float a[8] = {0.f, 0.f, 0.f, 0.f, 0.f, 0.f, 0.f, 0.f};
  float wbuf[8];
  int base = 9 * tid;
#pragma unroll
  for (int r = 0; r < 8; ++r) wbuf[r] = frp[base + r];
  int nbase = base + 9;
  for (int tau8 = 0; tau8 < 128; ++tau8) {
    int nb = nbase + tau8 * 9;
#pragma unroll
    for (int r = 0; r < 8; ++r) {
      float fv = fl[tau8 * 8 + r];
#pragma unroll
      for (int q = 0; q < 8; ++q)
        a[q] = fmaf(wbuf[(r + q) & 7], fv, a[q]);
      wbuf[r] = frp[nb + r];
    }
  }
#pragma unroll
  for (int q = 0; q < 8; ++q) {
    int i = tid * 8 + q;
    if (i < 1984) outf[((size_t)b * LF + t) * 1984 + i] = a[q];
  }
}

// ---------------- fold (plain stores; overwrites every output element) ----------------
__global__ void fold_kernel(const float* __restrict__ outf, float* __restrict__ out) {
  int idx = blockIdx.x * 256 + threadIdx.x;
  if (idx >= NB * LW) return;
  int b = idx / LW, n = idx % LW;
  int t0 = (n >= 1984) ? ((n - 1024) / 960) : 0;
  int t1 = n / 960; if (t1 > 199) t1 = 199;
  float acc = 0.f;
  for (int t = t0; t <= t1; ++t)
    acc += outf[((size_t)b * LF + t) * 1984 + (n - 960 * t)];
  out[idx] = acc;
}

extern "C" void kernel_launch(void* const* d_in, const int* in_sizes, int n_in,
                              void* d_out, int out_size, void* d_ws, size_t ws_size,
                              hipStream_t stream) {
  const float* content    = (const float*)d_in[0];
  const float* f0         = (const float*)d_in[1];
  const float* energy     = (const float*)d_in[2];
  const float* spk        = (const float*)d_in[3];
  const float* s_in_w     = (const float*)d_in[4];
  const float* s_in_b     = (const float*)d_in[5];
  const float* s_dw_w     = (const float*)d_in[6];
  const float* s_dw_b     = (const float*)d_in[7];
  const float* s_ln       = (const float*)d_in[8];
  const float* s_pw1_w    = (const float*)d_in[9];
  const float* s_pw1_b    = (const float*)d_in[10];
  const float* s_pw2_w    = (const float*)d_in[11];
  const float* s_pw2_b    = (const float*)d_in[12];
  const float* s_out_norm = (const float*)d_in[13];
  const float* f_in_w     = (const float*)d_in[14];
  const float* f_in_b     = (const float*)d_in[15];
  const float* f_dw_w     = (const float*)d_in[16];
  const float* f_dw_b     = (const float*)d_in[17];
  const float* f_ln       = (const float*)d_in[18];
  const float* f_pw1_w    = (const float*)d_in[19];
  const float* f_pw1_b    = (const float*)d_in[20];
  const float* f_pw2_w    = (const float*)d_in[21];
  const float* f_pw2_b    = (const float*)d_in[22];
  const float* f_out_norm = (const float*)d_in[23];
  const float* s_in_norm  = (const float*)d_in[24];
  const float* s_amp_w    = (const float*)d_in[25];
  const float* s_amp_b    = (const float*)d_in[26];
  const float* s_ker_w    = (const float*)d_in[27];
  const float* s_ker_b    = (const float*)d_in[28];
  const float* f_out_w    = (const float*)d_in[29];
  const float* f_out_b    = (const float*)d_in[30];

  // ---- workspace layout (unchanged) ----
  char* W0 = (char*)d_ws;
  double*   CSUM  = (double*)W0;                         // 12,032
  uint32_t* XINPH = (uint32_t*)(W0 + 12032);             // 3,072,000
  float*    XS    = (float*)   (W0 + 6156032);           // 6,553,600 (3200 x 512)
  uint32_t* TPH   = (uint32_t*)(W0 + 12709632);          // 3,276,800 (3200 x 256)
  uint16_t* KERH  = (uint16_t*)(W0 + 19263232);          // 6,147,200
  float*    AMPS  = (float*)   (W0 + 25410432);          // 8,192
  float*    FILT  = (float*)   (W0 + 25418624);          // 6,553,600
  float*    HARM  = (float*)   (W0 + 31972224);          // 6,144,000
  char*     R2    = W0 + 38116224;                       // 26,411,008
  char*     FTR   = W0 + 64527232;                       // 24,576,000
  char*     U     = W0 + 89103232;                       // 25,559,040
  uint32_t* TH32  = (uint32_t*)(W0 + 114662272);         // 30,474,240  (pw2 packs -> T -> V)
  float*    CTAB  = (float*)   (W0 + 175610752);         // 15,360 -> ends 175,626,112
  // overlays
  uint32_t* XSPH = TPH;                                  // (after trunk, TP dead)
  uint32_t* H15PH = (uint32_t*)R2;                       // 9,830,400 (3200 x 768) hi-only
  uint32_t* IMPH = (uint32_t*)R2;                        // 11,468,800 (after H15 dead)
  uint16_t* SH   = (uint16_t*)R2;                        // 13,205,504 (1664 x 3968, after IMP dead)
  float*    OUTF = (float*)R2;                           // 12,697,600 (after SH dead post-invNT)
  float*    FS   = (float*)FTR;                          // 6,144,000
  float*    FT   = (float*)FTR;                          // 24,576,000 (after FS dead)
  // weight-pack blobs (hi only):
  uint32_t* PW1PH_A = (uint32_t*)FTR;                    // layers 0-2 (dead before FS)
  uint32_t* PW1PH_B = (uint32_t*)U;                      // layers 3-5 (dead before ker/fout packs)
  uint32_t* PW2PH = TH32;                                // pw2 all 6 layers (dead before twfill_pk)
  uint32_t* WINPH = (uint32_t*)R2;                       // in-proj pack (dead before H15)
  uint32_t* WPH  = (uint32_t*)U;                         // ker/fout packs, post-trunk
  uint16_t* AH   = (uint16_t*)U;                         // noise A hi (after WP dead)

  (void)in_sizes; (void)n_in; (void)out_size; (void)ws_size;

  ctab_fill<<<dim3(15), 256, 0, stream>>>(CTAB);
  build_xin_pk<<<dim3((MB2 * 240 + 255) / 256), 256, 0, stream>>>(content, f0, energy, spk, XINPH);

  // ---- mega-pack all trunk weights upfront (hi only) ----
  {
    int perset = HID * 256;
    int tot3 = 3 * 2 * perset;
    pack_wN<<<dim3((tot3 + 255) / 256), 256, 0, stream>>>(s_pw1_w, f_pw1_w, (size_t)HID * CI,
        PW1PH_A, HID, CI, 256, perset, tot3);
    pack_wN<<<dim3((tot3 + 255) / 256), 256, 0, stream>>>(s_pw1_w + (size_t)3 * HID * CI,
        f_pw1_w + (size_t)3 * HID * CI, (size_t)HID * CI,
        PW1PH_B, HID, CI, 256, perset, tot3);
    int tot6 = 6 * 2 * perset;
    pack_wN<<<dim3((tot6 + 255) / 256), 256, 0, stream>>>(s_pw2_w, f_pw2_w, (size_t)CI * HID,
        PW2PH, CI, HID, 768, perset, tot6);
  }
  {
    int total = CI * 240;
    pack_w2<<<dim3((2 * total + 255) / 256), 256, 0, stream>>>(s_in_w, f_in_w, WINPH, CI, CIN, 240, total);
  }

  // ---- batched dual-trunk (64x64 tiles, single-bf16) ----
  gemm_bf<<<dim3(8 * 50), 256, 0, stream>>>((uint16_t*)WINPH, (uint16_t*)XINPH,
      s_in_b, f_in_b, nullptr, XS, nullptr, CI, 480, 8, 50, 0, 0, 25, (size_t)512 * 480);
  ln2_kernel<<<dim3(MTOT / 4), 256, 0, stream>>>(XS, s_in_norm, s_in_norm + CI, nullptr);
  for (int i = 0; i < NL; ++i) {
    dwln_kernel<<<dim3(MB2), 256, 0, stream>>>(XS,
        s_dw_w + (size_t)i * CI * 7, s_dw_b + (size_t)i * CI,
        s_ln + (size_t)(i * 2) * CI, s_ln + (size_t)(i * 2 + 1) * CI,
        f_dw_w + (size_t)i * CI * 7, f_dw_b + (size_t)i * CI,
        f_ln + (size_t)(i * 2) * CI, f_ln + (size_t)(i * 2 + 1) * CI,
        TPH);
    const uint16_t* w1h = (i < 3) ? (const uint16_t*)((char*)PW1PH_A + (size_t)i * 3145728)
                                  : (const uint16_t*)((char*)PW1PH_B + (size_t)(i - 3) * 3145728);
    gemm_bf<<<dim3(24 * 50), 256, 0, stream>>>(w1h, (uint16_t*)TPH,
        s_pw1_b + (size_t)i * HID, f_pw1_b + (size_t)i * HID, nullptr,
        nullptr, (uint16_t*)H15PH, HID, 512, 24, 50, 1, 1, 25, (size_t)1536 * 512);
    const uint16_t* w2h = (const uint16_t*)((char*)PW2PH + (size_t)i * 3145728);
    gemm_bf<<<dim3(8 * 50), 256, 0, stream>>>(w2h, (uint16_t*)H15PH,
        s_pw2_b + (size_t)i * CI, f_pw2_b + (size_t)i * CI, XS,
        XS, nullptr, CI, 1536, 8, 50, 0, 0, 25, (size_t)512 * 1536);
  }

  // ---- heads ----
  ln2_kernel<<<dim3(MTOT / 4), 256, 0, stream>>>(XS, s_out_norm, s_out_norm + CI, XSPH);
  amps2_kernel<<<dim3(MTOT / 4), 256, 0, stream>>>(XS, s_amp_w, s_amp_b, AMPS);
  {
    int total = 1984 * 256;
    pack_w<<<dim3((total + 255) / 256), 256, 0, stream>>>(s_ker_w, WPH, NFREQ, CI, 256, total);
  }
  gemm_bf<<<dim3(31 * 25), 256, 0, stream>>>((uint16_t*)WPH, (uint16_t*)XSPH,
      s_ker_b, nullptr, nullptr, nullptr, KERH, NFREQ, 512, 31, 25, 2, 2, 1000, 0);

  ln2_kernel<<<dim3(MTOT / 4), 256, 0, stream>>>(XS + (size_t)MTOT * CI, f_out_norm, f_out_norm + CI, nullptr);
  im2col_pk<<<dim3((MTOT * 1792 + 255) / 256), 256, 0, stream>>>(XS + (size_t)MTOT * CI, IMPH);
  {
    int total = NWIN * 1792;
    pack_w<<<dim3((total + 255) / 256), 256, 0, stream>>>(f_out_w, WPH, NWIN, 3584, 1792, total);
  }
  gemm_bf<<<dim3(16 * 25), 256, 0, stream>>>((uint16_t*)WPH, (uint16_t*)IMPH,
      f_out_b, nullptr, nullptr, FILT, nullptr, NWIN, 3584, 16, 25, 0, 0, 1000, 0);

  // ---- harmonic source (FS lives in FT region, dead before inv) ----
  cumsum1<<<dim3(NCH, NB), 256, 0, stream>>>(f0, FS, CSUM);
  harm_kernel<<<dim3(NCH, NB), 256, 0, stream>>>(FS, CSUM, f0, AMPS, HARM);

  // ---- filtered noise: fwd (T table) then inv (V table overwrites T), single-bf16, 128x128 x 512thr ----
  pack_noise<<<dim3((MPAD * 1920 + 255) / 256), 256, 0, stream>>>(CTAB, (uint32_t*)AH);
  twfill_pk<<<dim3((SWID * 1920 + 255) / 256), 256, 0, stream>>>(CTAB, TH32);
  gemm_fwd128<<<dim3(13 * 31), 512, 0, stream>>>((uint16_t*)AH, (uint16_t*)TH32, KERH, SH);
  twfill_v<<<dim3((NFFT * (SWID / 2) + 255) / 256), 256, 0, stream>>>(CTAB, TH32);
  gemm_invNT<<<dim3(30 * 13), 512, 0, stream>>>(SH, (uint16_t*)TH32, CTAB, FT);

  // ---- fused OLA + FIR (plain stores) + fold ----
  fir5_kernel<<<dim3(LF, NB), 256, 0, stream>>>(FT, HARM, FILT, CTAB, OUTF);
  fold_kernel<<<dim3((NB * LW + 255) / 256), 256, 0, stream>>>(OUTF, (float*)d_out);
}

// Round 22
// 866.262 us; speedup vs baseline: 1.0870x; 1.0065x over previous
//
#include <hip/hip_runtime.h>
#include <hip/hip_bf16.h>
#include <math.h>
#include <stdint.h>

#define FRAME 960
#define NFFT  3840
#define NWIN  1024
#define NFREQ 1921
#define NB    8
#define LF    200
#define LW    192000
#define CIN   450
#define CI    512
#define HID   1536
#define NL    6
#define NCH   188
#define NK2   3842
#define MTOT  1600
#define MB2   3200   // both trunks batched
#define SWID  3968   // padded spec width
#define MPAD  1664   // padded frame rows for DFT

typedef __attribute__((ext_vector_type(8))) short short8v;
typedef __attribute__((ext_vector_type(4))) float f32x4;
typedef __attribute__((address_space(3))) uint32_t lds_u32;
typedef const __attribute__((address_space(1))) uint32_t glb_u32;

// ---------------- threefry (JAX partitionable) ----------------
__device__ __forceinline__ uint32_t rotl32(uint32_t v, int r) { return (v << r) | (v >> (32 - r)); }
__device__ __forceinline__ void threefry2x32(uint32_t k0, uint32_t k1, uint32_t& x0, uint32_t& x1) {
  uint32_t ks2 = k0 ^ k1 ^ 0x1BD11BDAu;
  x0 += k0; x1 += k1;
#define TFR(r) { x0 += x1; x1 = rotl32(x1, r); x1 ^= x0; }
  TFR(13) TFR(15) TFR(26) TFR(6)  x0 += k1;  x1 += ks2 + 1u;
  TFR(17) TFR(29) TFR(16) TFR(24) x0 += ks2; x1 += k0 + 2u;
  TFR(13) TFR(15) TFR(26) TFR(6)  x0 += k0;  x1 += k1 + 3u;
  TFR(17) TFR(29) TFR(16) TFR(24) x0 += k1;  x1 += ks2 + 4u;
  TFR(13) TFR(15) TFR(26) TFR(6)  x0 += ks2; x1 += k0 + 5u;
#undef TFR
}
__device__ __forceinline__ float noiseval(int b, int m) {
  if (m < 0) m = -m;
  if (m >= LW) m = 2 * LW - 2 - m;
  uint32_t x0 = 0u, x1 = (uint32_t)(b * LW + m);
  threefry2x32(0u, 123u, x0, x1);
  uint32_t bits = x0 ^ x1;
  return __uint_as_float((bits >> 9) | 0x3f800000u) - 1.0f;
}
__device__ __forceinline__ float winf(int j) {
  return 0.5f - 0.5f * cosf((6.283185307179586f * (float)j) / 3840.0f);
}
__device__ __forceinline__ unsigned short f2bf(float v) {
  uint32_t b = __float_as_uint(v);
  return (unsigned short)((b + 0x7FFFu + ((b >> 16) & 1u)) >> 16);
}
__device__ __forceinline__ float bf2f(unsigned short h) {
  return __uint_as_float(((uint32_t)h) << 16);
}
__device__ __forceinline__ uint32_t pack2(float a, float b, bool lo) {
  unsigned short ha = f2bf(a), hb = f2bf(b);
  if (!lo) return (uint32_t)ha | ((uint32_t)hb << 16);
  return (uint32_t)f2bf(a - bf2f(ha)) | ((uint32_t)f2bf(b - bf2f(hb)) << 16);
}
__device__ __forceinline__ int xcd_remap(int lin, int nwg) {
  int q = nwg >> 3, r = nwg & 7;
  int xcd = lin & 7, base = lin >> 3;
  int start = (xcd < r) ? xcd * (q + 1) : r * (q + 1) + (xcd - r) * q;
  return start + base;
}

// ---------------- cos table (3840 f32), bit-matching winf's cos argument ----------------
__global__ void ctab_fill(float* __restrict__ ct) {
  int j = blockIdx.x * 256 + threadIdx.x;
  if (j < NFFT) ct[j] = cosf((6.283185307179586f * (float)j) / 3840.0f);
}

// ---------------- xin packed (hi only), duplicated for both trunks ----------------
__global__ void build_xin_pk(const float* __restrict__ content, const float* __restrict__ f0,
                             const float* __restrict__ energy, const float* __restrict__ spk,
                             uint32_t* __restrict__ PH) {
  int idx = blockIdx.x * 256 + threadIdx.x;
  if (idx >= MB2 * 240) return;
  int row = idx / 240, cp = idx % 240;
  int rb = row % MTOT;
  int b = rb / LF, l = rb % LF;
  float v2[2];
#pragma unroll
  for (int u = 0; u < 2; ++u) {
    int c = cp * 2 + u;
    float v = 0.f;
    if (c < 192)       v = content[((size_t)b * 192 + c) * LF + l];
    else if (c < 448)  v = spk[b * 256 + (c - 192)];
    else if (c == 448) v = logf(fmaxf(f0[b * LF + l], 0.0f) + 1e-6f);
    else if (c == 449) v = energy[b * LF + l];
    v2[u] = v;
  }
  PH[idx] = pack2(v2[0], v2[1], false);
}

// ---------------- weight pack (single set, hi only) ----------------
__global__ void pack_w(const float* __restrict__ W, uint32_t* __restrict__ PH,
                       int M, int K, int Kp2, int total) {
  int idx = blockIdx.x * 256 + threadIdx.x;
  if (idx >= total) return;
  int m = idx / Kp2, kp = idx % Kp2;
  int k = kp * 2;
  float v0 = (m < M && k < K) ? W[(size_t)m * K + k] : 0.f;
  float v1 = (m < M && (k + 1) < K) ? W[(size_t)m * K + k + 1] : 0.f;
  PH[idx] = pack2(v0, v1, false);
}

// ---------------- weight pack (dual set, one dispatch, hi only) ----------------
__global__ void pack_w2(const float* __restrict__ Ws, const float* __restrict__ Wf,
                        uint32_t* __restrict__ PH, int M, int K, int Kp2, int total) {
  int idx = blockIdx.x * 256 + threadIdx.x;
  if (idx >= 2 * total) return;
  int half = idx >= total;
  const float* W = half ? Wf : Ws;
  int t = idx - half * total;
  int m = t / Kp2, kp = t % Kp2;
  int k = kp * 2;
  float v0 = (m < M && k < K) ? W[(size_t)m * K + k] : 0.f;
  float v1 = (m < M && (k + 1) < K) ? W[(size_t)m * K + k + 1] : 0.f;
  PH[idx] = pack2(v0, v1, false);
}

// ---------------- weight pack (dual set, N layers, one dispatch, hi only) ----------------
__global__ void pack_wN(const float* __restrict__ Ws, const float* __restrict__ Wf, size_t lstride,
                        uint32_t* __restrict__ PH, int M, int K, int Kp2, int perset, int total) {
  int idx = blockIdx.x * 256 + threadIdx.x;
  if (idx >= total) return;
  int l = idx / (2 * perset);
  int r = idx - l * 2 * perset;
  int half = r >= perset;
  const float* W = (half ? Wf : Ws) + (size_t)l * lstride;
  int t = r - half * perset;
  int m = t / Kp2, kp = t % Kp2;
  int k = kp * 2;
  float v0 = (m < M && k < K) ? W[(size_t)m * K + k] : 0.f;
  float v1 = (m < M && (k + 1) < K) ? W[(size_t)m * K + k + 1] : 0.f;
  PH[idx] = pack2(v0, v1, false);
}

// ---------------- single-bf16 NT GEMM, 64x64 tile, dual-weight-set batched ----------------
__global__ __launch_bounds__(256) void gemm_bf(
    const uint16_t* __restrict__ WH, const uint16_t* __restrict__ XH,
    const float* __restrict__ bias, const float* __restrict__ bias2,
    const float* __restrict__ res,
    float* __restrict__ outF, uint16_t* __restrict__ outH,
    int M, int Kp, int mtiles, int ntiles, int mode, int act, int nsp, size_t woff)
{
  __shared__ __align__(16) char smem[2][2][4096];
  int nwg = mtiles * ntiles;
  int wg = xcd_remap(blockIdx.x, nwg);
  int mtile = wg / ntiles, ntile = wg % ntiles;
  int m0 = mtile * 64, n0 = ntile * 64;
  int tid = threadIdx.x;
  int lane = tid & 63, w = tid >> 6;
  int wm = w >> 1, wn = w & 1;
  int rowg = Kp >> 3;
  int phases = Kp >> 5;

  int opsel = w >> 1, whalf = w & 1;
  const uint16_t* gb = (opsel == 0) ? WH : XH;
  if (opsel == 0 && ntile >= nsp) gb += woff;
  int row0 = (opsel == 0) ? m0 : n0;
  f32x4 acc[2][2];
#pragma unroll
  for (int i = 0; i < 2; ++i)
#pragma unroll
    for (int j = 0; j < 2; ++j) acc[i][j] = (f32x4){0.f, 0.f, 0.f, 0.f};

  auto stage = [&](int buf, int p) {
    int kg0 = p * 4;
#pragma unroll
    for (int c = 0; c < 2; ++c) {
      int i = whalf * 2 + c;
      int r = i * 16 + (lane >> 2);
      int scg = lane & 3;
      int sgsel = scg ^ (((lane >> 2) >> 1) & 3);
      const uint16_t* src = gb + (size_t)(row0 + r) * rowg * 8 + (size_t)(kg0 + sgsel) * 8;
      __builtin_amdgcn_global_load_lds((glb_u32*)src, (lds_u32*)(&smem[buf][opsel][0] + i * 1024), 16, 0, 0);
    }
  };

  stage(0, 0);
  __syncthreads();
  int fr = lane & 15, fg = lane >> 4;
  int fsw = ((fr >> 1) & 3);
  int aoff0 = (wm * 32 + fr) * 64 + (fg ^ fsw) * 16;
  int aoff1 = (wm * 32 + 16 + fr) * 64 + (fg ^ fsw) * 16;
  int boff0 = (wn * 32 + fr) * 64 + (fg ^ fsw) * 16;
  int boff1 = (wn * 32 + 16 + fr) * 64 + (fg ^ fsw) * 16;

  for (int p = 0; p < phases; ++p) {
    int cur = p & 1;
    if (p + 1 < phases) stage(cur ^ 1, p + 1);
    short8v ah0 = *(const short8v*)(&smem[cur][0][0] + aoff0);
    short8v ah1 = *(const short8v*)(&smem[cur][0][0] + aoff1);
    short8v bh0 = *(const short8v*)(&smem[cur][1][0] + boff0);
    short8v bh1 = *(const short8v*)(&smem[cur][1][0] + boff1);
    acc[0][0] = __builtin_amdgcn_mfma_f32_16x16x32_bf16(ah0, bh0, acc[0][0], 0, 0, 0);
    acc[0][1] = __builtin_amdgcn_mfma_f32_16x16x32_bf16(ah0, bh1, acc[0][1], 0, 0, 0);
    acc[1][0] = __builtin_amdgcn_mfma_f32_16x16x32_bf16(ah1, bh0, acc[1][0], 0, 0, 0);
    acc[1][1] = __builtin_amdgcn_mfma_f32_16x16x32_bf16(ah1, bh1, acc[1][1], 0, 0, 0);
    __syncthreads();
  }

#pragma unroll
  for (int mi = 0; mi < 2; ++mi)
#pragma unroll
    for (int ni = 0; ni < 2; ++ni)
#pragma unroll
      for (int r = 0; r < 4; ++r) {
        int m = m0 + wm * 32 + mi * 16 + ((lane >> 4) << 2) + r;
        int n = n0 + wn * 32 + ni * 16 + (lane & 15);
        if (m >= M) continue;
        float v = acc[mi][ni][r];
        if (bias) v += (bias2 && n >= nsp * 64) ? bias2[m] : bias[m];
        if (act == 1)      v = 0.5f * v * (1.0f + erff(v * 0.7071067811865475f));
        else if (act == 2) v = (v > 0.f ? v : expm1f(v)) + 1.0f;
        if (mode == 0) {
          if (res) v += res[(size_t)n * M + m];
          outF[(size_t)n * M + m] = v;
        } else if (mode == 1) {
          outH[(size_t)n * M + m] = f2bf(v);
        } else {  // 2: KER bf16 (NFREQ row stride)
          outH[(size_t)n * NFREQ + m] = f2bf(v);
        }
      }
}

// ---------------- fwd DFT GEMM: 128x128 tile, 512 threads (8 waves, 2x4), single-bf16 ----------------
__global__ __launch_bounds__(512) void gemm_fwd128(
    const uint16_t* __restrict__ AH, const uint16_t* __restrict__ TH,
    const uint16_t* __restrict__ KERH, uint16_t* __restrict__ SH)
{
  __shared__ __align__(16) char smem[2][2][8192];
  int wg = xcd_remap(blockIdx.x, 13 * 31);
  int ntile = wg / 13, mtile = wg % 13;   // m-inner: T-tile L2-resident
  int m0 = mtile * 128, n0 = ntile * 128;
  int tid = threadIdx.x;
  int lane = tid & 63, w = tid >> 6;      // 8 waves
  int wm = w >> 2, wn = w & 3;            // 2x4: each wave owns 64x32
  f32x4 acc[4][2];
#pragma unroll
  for (int i = 0; i < 4; ++i)
#pragma unroll
    for (int j = 0; j < 2; ++j) acc[i][j] = (f32x4){0.f, 0.f, 0.f, 0.f};

  auto stage = [&](int buf, int p) {
#pragma unroll
    for (int c = 0; c < 2; ++c) {
      int ci = w * 2 + c;                 // 16 chunks: 0-7 A, 8-15 B
      int opsel = ci >> 3;
      int cc = ci & 7;
      int gl = cc * 64 + lane;
      int row = gl >> 2, cg = gl & 3;
      int sg = cg ^ ((row >> 1) & 3);
      const uint16_t* src = (opsel ? TH + (size_t)(n0 + row) * 3840 : AH + (size_t)(m0 + row) * 3840)
                            + p * 32 + sg * 8;
      __builtin_amdgcn_global_load_lds((glb_u32*)src, (lds_u32*)(&smem[buf][opsel][0] + cc * 1024), 16, 0, 0);
    }
  };

  stage(0, 0);
  __syncthreads();
  int fr = lane & 15, fg = lane >> 4;

  for (int p = 0; p < 120; ++p) {
    int cur = p & 1;
    if (p + 1 < 120) stage(cur ^ 1, p + 1);
    short8v a_h[4], b_h[2];
#pragma unroll
    for (int q = 0; q < 4; ++q) {
      int ra = wm * 64 + q * 16 + fr;
      a_h[q] = *(const short8v*)(&smem[cur][0][0] + ra * 64 + ((fg ^ ((ra >> 1) & 3)) << 4));
    }
#pragma unroll
    for (int s = 0; s < 2; ++s) {
      int rb = wn * 32 + s * 16 + fr;
      b_h[s] = *(const short8v*)(&smem[cur][1][0] + rb * 64 + ((fg ^ ((rb >> 1) & 3)) << 4));
    }
#pragma unroll
    for (int mi = 0; mi < 4; ++mi)
#pragma unroll
      for (int ni = 0; ni < 2; ++ni)
        acc[mi][ni] = __builtin_amdgcn_mfma_f32_16x16x32_bf16(a_h[mi], b_h[ni], acc[mi][ni], 0, 0, 0);
    __syncthreads();
  }

#pragma unroll
  for (int mi = 0; mi < 4; ++mi)
#pragma unroll
    for (int ni = 0; ni < 2; ++ni)
#pragma unroll
      for (int r = 0; r < 4; ++r) {
        int m = m0 + wm * 64 + mi * 16 + ((lane >> 4) << 2) + r;
        int n = n0 + wn * 32 + ni * 16 + (lane & 15);
        if (m < MTOT) {
          float o = 0.f;
          if (n < NK2) {
            int k = n >> 1;
            float kv = bf2f(KERH[(size_t)m * NFREQ + k]);
            bool edge = (k == 0) || (k == 1920);
            float mult = edge ? (1.0f / NFFT) : (2.0f / NFFT);
            o = acc[mi][ni][r] * kv * mult;
            if ((n & 1) && edge) o = 0.f;
          }
          SH[(size_t)m * SWID + n] = f2bf(o);
        }
      }
}

// ---------------- transposed twiddle V[j][k2] via cos table (hi only; overwrites T after fwd) ----------------
__global__ void twfill_v(const float* __restrict__ ct, uint32_t* __restrict__ VH) {
  int idx = blockIdx.x * 256 + threadIdx.x;
  if (idx >= NFFT * (SWID / 2)) return;
  int j = idx / (SWID / 2), kp = idx % (SWID / 2);
  float v2[2] = {0.f, 0.f};
#pragma unroll
  for (int u = 0; u < 2; ++u) {
    int k2 = kp * 2 + u;
    if (k2 < NK2) {
      int k = k2 >> 1;
      int m = (j * k) % NFFT;
      m += (k2 & 1) * 960;               // -sin(x) = cos(x + pi/2)
      if (m >= NFFT) m -= NFFT;
      v2[u] = ct[m];
    }
  }
  VH[idx] = pack2(v2[0], v2[1], false);
}

// ---------------- inverse DFT as pure NT GEMM: 128x128 tile, 512 threads; window via ctab ----------------
__global__ __launch_bounds__(512) void gemm_invNT(
    const uint16_t* __restrict__ SH, const uint16_t* __restrict__ VH,
    const float* __restrict__ ct, float* __restrict__ ft)
{
  __shared__ __align__(16) char smem[2][2][8192];
  int wg = xcd_remap(blockIdx.x, 30 * 13);
  int ntile = wg / 13, mtile = wg % 13;   // m-inner: V-tile L2-resident
  int m0 = mtile * 128, n0 = ntile * 128;
  int tid = threadIdx.x;
  int lane = tid & 63, w = tid >> 6;
  int wm = w >> 2, wn = w & 3;
  f32x4 acc[4][2];
#pragma unroll
  for (int i = 0; i < 4; ++i)
#pragma unroll
    for (int j = 0; j < 2; ++j) acc[i][j] = (f32x4){0.f, 0.f, 0.f, 0.f};

  auto stage = [&](int buf, int p) {
#pragma unroll
    for (int c = 0; c < 2; ++c) {
      int ci = w * 2 + c;
      int opsel = ci >> 3;
      int cc = ci & 7;
      int gl = cc * 64 + lane;
      int row = gl >> 2, cg = gl & 3;
      int sg = cg ^ ((row >> 1) & 3);
      const uint16_t* src = (opsel ? VH + (size_t)(n0 + row) * SWID : SH + (size_t)(m0 + row) * SWID)
                            + p * 32 + sg * 8;
      __builtin_amdgcn_global_load_lds((glb_u32*)src, (lds_u32*)(&smem[buf][opsel][0] + cc * 1024), 16, 0, 0);
    }
  };

  stage(0, 0);
  __syncthreads();
  int fr = lane & 15, fg = lane >> 4;

  for (int p = 0; p < 124; ++p) {
    int cur = p & 1;
    if (p + 1 < 124) stage(cur ^ 1, p + 1);
    short8v a_h[4], b_h[2];
#pragma unroll
    for (int q = 0; q < 4; ++q) {
      int ra = wm * 64 + q * 16 + fr;
      a_h[q] = *(const short8v*)(&smem[cur][0][0] + ra * 64 + ((fg ^ ((ra >> 1) & 3)) << 4));
    }
#pragma unroll
    for (int s = 0; s < 2; ++s) {
      int rb = wn * 32 + s * 16 + fr;
      b_h[s] = *(const short8v*)(&smem[cur][1][0] + rb * 64 + ((fg ^ ((rb >> 1) & 3)) << 4));
    }
#pragma unroll
    for (int mi = 0; mi < 4; ++mi)
#pragma unroll
      for (int ni = 0; ni < 2; ++ni)
        acc[mi][ni] = __builtin_amdgcn_mfma_f32_16x16x32_bf16(a_h[mi], b_h[ni], acc[mi][ni], 0, 0, 0);
    __syncthreads();
  }

#pragma unroll
  for (int mi = 0; mi < 4; ++mi)
#pragma unroll
    for (int ni = 0; ni < 2; ++ni)
#pragma unroll
      for (int r = 0; r < 4; ++r) {
        int m = m0 + wm * 64 + mi * 16 + ((lane >> 4) << 2) + r;
        int n = n0 + wn * 32 + ni * 16 + (lane & 15);
        if (m < MTOT) ft[(size_t)m * NFFT + n] = acc[mi][ni][r] * (0.5f - 0.5f * ct[n]);
      }
}

// ---------------- LayerNorm rows, optional packed out (hi only) ----------------
__global__ __launch_bounds__(256) void ln2_kernel(float* __restrict__ x, const float* __restrict__ g,
                                                  const float* __restrict__ bta,
                                                  uint32_t* __restrict__ PH) {
  int row = blockIdx.x * 4 + (threadIdx.x >> 6);
  int lane = threadIdx.x & 63;
  float* xr = x + (size_t)row * CI;
  int c0 = lane * 8;
  float4 v0 = *(float4*)&xr[c0], v1 = *(float4*)&xr[c0 + 4];
  float s = v0.x + v0.y + v0.z + v0.w + v1.x + v1.y + v1.z + v1.w;
#pragma unroll
  for (int m = 1; m < 64; m <<= 1) s += __shfl_xor(s, m, 64);
  float mean = s * (1.0f / CI);
  float d[8] = {v0.x - mean, v0.y - mean, v0.z - mean, v0.w - mean,
                v1.x - mean, v1.y - mean, v1.z - mean, v1.w - mean};
  float s2 = 0.f;
#pragma unroll
  for (int q = 0; q < 8; ++q) s2 += d[q] * d[q];
#pragma unroll
  for (int m = 1; m < 64; m <<= 1) s2 += __shfl_xor(s2, m, 64);
  float rs = rsqrtf(s2 * (1.0f / CI) + 1e-5f);
  float o[8];
#pragma unroll
  for (int q = 0; q < 8; ++q) o[q] = d[q] * rs * g[c0 + q] + bta[c0 + q];
  float4 w0 = {o[0], o[1], o[2], o[3]}, w1 = {o[4], o[5], o[6], o[7]};
  *(float4*)&xr[c0] = w0; *(float4*)&xr[c0 + 4] = w1;
  if (PH) {
    int base = (row * CI + c0) >> 1;
#pragma unroll
    for (int q = 0; q < 4; ++q)
      PH[base + q] = pack2(o[2 * q], o[2 * q + 1], false);
  }
}

// ---------------- fused dwconv K=7 + LN -> packed (hi only), dual-trunk batched ----------------
__global__ __launch_bounds__(256) void dwln_kernel(const float* __restrict__ xs,
    const float* __restrict__ dws, const float* __restrict__ dbs,
    const float* __restrict__ gs, const float* __restrict__ bts,
    const float* __restrict__ dwf, const float* __restrict__ dbf,
    const float* __restrict__ gf, const float* __restrict__ btf,
    uint32_t* __restrict__ PH) {
  int row = blockIdx.x;
  int half = row >= MTOT;
  const float* dw = half ? dwf : dws;
  const float* db = half ? dbf : dbs;
  const float* g  = half ? gf : gs;
  const float* bt = half ? btf : bts;
  int rb = row - half * MTOT;
  int b = rb / LF, l = rb % LF;
  int rbase = half * MTOT + b * LF;
  int c = threadIdx.x * 2;
  float ax = db[c], ay = db[c + 1];
#pragma unroll
  for (int tau = 0; tau < 7; ++tau) {
    int j = l + tau - 3;
    if (j < 0 || j >= LF) continue;
    float2 xv = *(const float2*)&xs[((size_t)(rbase + j)) * CI + c];
    ax = fmaf(xv.x, dw[c * 7 + tau], ax);
    ay = fmaf(xv.y, dw[(c + 1) * 7 + tau], ay);
  }
  __shared__ float red[4], red2[4];
  float s = ax + ay;
#pragma unroll
  for (int m = 1; m < 64; m <<= 1) s += __shfl_xor(s, m, 64);
  if ((threadIdx.x & 63) == 0) red[threadIdx.x >> 6] = s;
  __syncthreads();
  float mean = (red[0] + red[1] + red[2] + red[3]) * (1.0f / CI);
  float dx = ax - mean, dy = ay - mean;
  float s2 = dx * dx + dy * dy;
#pragma unroll
  for (int m = 1; m < 64; m <<= 1) s2 += __shfl_xor(s2, m, 64);
  if ((threadIdx.x & 63) == 0) red2[threadIdx.x >> 6] = s2;
  __syncthreads();
  float var = (red2[0] + red2[1] + red2[2] + red2[3]) * (1.0f / CI);
  float rs = rsqrtf(var + 1e-5f);
  float vx = dx * rs * g[c] + bt[c];
  float vy = dy * rs * g[c + 1] + bt[c + 1];
  PH[(size_t)row * 256 + threadIdx.x] = pack2(vx, vy, false);
}

// ---------------- amps head ----------------
__global__ __launch_bounds__(256) void amps2_kernel(const float* __restrict__ x, const float* __restrict__ w,
                                                    const float* __restrict__ bias, float* __restrict__ amps) {
  int row = blockIdx.x * 4 + (threadIdx.x >> 6);
  int lane = threadIdx.x & 63;
  const float* xr = x + (size_t)row * CI;
  int c0 = lane * 8;
  float4 v0 = *(const float4*)&xr[c0], v1 = *(const float4*)&xr[c0 + 4];
  float4 w0 = *(const float4*)&w[c0], w1 = *(const float4*)&w[c0 + 4];
  float s = v0.x * w0.x + v0.y * w0.y + v0.z * w0.z + v0.w * w0.w
          + v1.x * w1.x + v1.y * w1.y + v1.z * w1.z + v1.w * w1.w;
#pragma unroll
  for (int m = 1; m < 64; m <<= 1) s += __shfl_xor(s, m, 64);
  if (lane == 0) {
    float a = s + bias[0];
    amps[row] = (a > 0.f ? a : expm1f(a)) + 1.0f;
  }
}

// ---------------- im2col packed (edge pad 3), hi only ----------------
__global__ void im2col_pk(const float* __restrict__ x, uint32_t* __restrict__ PH) {
  int idx = blockIdx.x * 256 + threadIdx.x;
  if (idx >= MTOT * 1792) return;
  int row = idx / 1792, kp = idx % 1792;
  int b = row / LF, l = row % LF;
  float v2[2];
#pragma unroll
  for (int u = 0; u < 2; ++u) {
    int kap = kp * 2 + u;
    int ch = kap / 7, tau = kap % 7;
    int j = l + tau - 3;
    j = j < 0 ? 0 : (j > LF - 1 ? LF - 1 : j);
    v2[u] = x[((size_t)b * LF + j) * CI + ch];
  }
  PH[idx] = pack2(v2[0], v2[1], false);
}

// ---------------- noise*window packed A hi (1664 x 3840); window via ctab ----------------
__global__ void pack_noise(const float* __restrict__ ct, uint32_t* __restrict__ AH) {
  int idx = blockIdx.x * 256 + threadIdx.x;
  if (idx >= MPAD * 1920) return;
  int t = idx / 1920, jp = idx % 1920;
  float v0 = 0.f, v1 = 0.f;
  if (t < MTOT) {
    int b = t / LF, tt = t % LF;
    int j = jp * 2;
    v0 = noiseval(b, tt * 960 + j - 960) * (0.5f - 0.5f * ct[j]);
    v1 = noiseval(b, tt * 960 + j - 959) * (0.5f - 0.5f * ct[j + 1]);
  }
  AH[idx] = pack2(v0, v1, false);
}

// ---------------- twiddle table hi T[k2][j] via cos table ----------------
__global__ void twfill_pk(const float* __restrict__ ct, uint32_t* __restrict__ TH) {
  int idx = blockIdx.x * 256 + threadIdx.x;
  if (idx >= SWID * 1920) return;
  int k2 = idx / 1920, jp = idx % 1920;
  float v2[2] = {0.f, 0.f};
  if (k2 < NK2) {
    int k = k2 >> 1;
    int add = (k2 & 1) * 960;
#pragma unroll
    for (int u = 0; u < 2; ++u) {
      int j = jp * 2 + u;
      int m = (j * k) % NFFT;
      m += add;
      if (m >= NFFT) m -= NFFT;
      v2[u] = ct[m];
    }
  }
  TH[idx] = pack2(v2[0], v2[1], false);
}

// ---------------- harmonic path: fs interp fused into cumsum1; csum holds RAW chunk sums ----------------
__global__ __launch_bounds__(256) void cumsum1(const float* __restrict__ f0, float* __restrict__ fs,
                                               double* __restrict__ csum) {
  int b = blockIdx.y, ch = blockIdx.x;
  int base = ch * 1024;
  double s = 0.0;
  for (int q = 0; q < 4; ++q) {
    int n = base + threadIdx.x * 4 + q;
    if (n < LW) {
      float pos = ((float)n + 0.5f) * (200.0f / 192000.0f) - 0.5f;
      pos = fminf(fmaxf(pos, 0.0f), 199.0f);
      int i0 = (int)pos;
      int i1 = min(i0 + 1, 199);
      float w = pos - (float)i0;
      float fsv = f0[b * LF + i0] * (1.0f - w) + f0[b * LF + i1] * w;
      fs[(size_t)b * LW + n] = fsv;
      s += (double)((3.14159274101257324f * fsv) / 48000.0f);
    }
  }
  __shared__ double sh[256];
  sh[threadIdx.x] = s;
  __syncthreads();
  for (int o2 = 128; o2 > 0; o2 >>= 1) {
    if (threadIdx.x < o2) sh[threadIdx.x] += sh[threadIdx.x + o2];
    __syncthreads();
  }
  if (threadIdx.x == 0) csum[b * NCH + ch] = sh[0];
}

__global__ __launch_bounds__(256) void harm_kernel(
    const float* __restrict__ fs, const double* __restrict__ csum,
    const float* __restrict__ f0, const float* __restrict__ amps,
    float* __restrict__ harm) {
  int b = blockIdx.y, ch = blockIdx.x;
  const float* fsb = fs + (size_t)b * LW;
  int base = ch * 1024;
  int tid = threadIdx.x;
  double p[4]; double s = 0.0;
  int n0 = base + tid * 4;
  for (int q = 0; q < 4; ++q) {
    int n = n0 + q; float sm = 0.f;
    if (n < LW) sm = (3.14159274101257324f * fsb[n]) / 48000.0f;
    s += (double)sm; p[q] = s;
  }
  __shared__ double sh[256];
  sh[tid] = (tid < ch) ? csum[b * NCH + tid] : 0.0;
  __syncthreads();
  for (int o2 = 128; o2 > 0; o2 >>= 1) {
    if (tid < o2) sh[tid] += sh[tid + o2];
    __syncthreads();
  }
  double cbase = sh[0];
  __syncthreads();
  sh[tid] = s; __syncthreads();
  for (int o2 = 1; o2 < 256; o2 <<= 1) {
    double v = (tid >= o2) ? sh[tid - o2] : 0.0;
    __syncthreads();
    sh[tid] += v;
    __syncthreads();
  }
  double excl = cbase + (tid > 0 ? sh[tid - 1] : 0.0);
  const double PID = (double)3.14159274101257324f;
  for (int q = 0; q < 4; ++q) {
    int n = n0 + q; if (n >= LW) break;
    double S = excl + p[q];
    float pixf = (float)fmod(S, PID);
    float fsv = fsb[n];
    float a = rintf(48000.0f / fmaxf(fsv, 20.0f) * 0.5f) * 2.0f + 1.0f;
    float D = (pixf < 1e-8f) ? 1.0f : (sinf(a * pixf) / (a * sinf(pixf)));
    int ui = n / 960;
    float uv = (f0[b * LF + ui] > 20.0f) ? 1.0f : 0.0f;
    float posA = ((float)n + 0.5f) * (200.0f / 192000.0f) - 0.5f;
    posA = fminf(fmaxf(posA, 0.0f), 199.0f);
    int i0 = (int)posA;
    int i1 = min(i0 + 1, 199);
    float w = posA - (float)i0;
    float ampI = amps[b * LF + i0] * (1.0f - w) + amps[b * LF + i1] * w;
    harm[(size_t)b * LW + n] = (D * uv) * ampI;
  }
}

// ---------------- fused OLA + FIR -> per-frame output; per-wave tau8 bounds skip zero band ----------------
__global__ __launch_bounds__(256) void fir5_kernel(const float* __restrict__ ft,
                                                   const float* __restrict__ harm,
                                                   const float* __restrict__ filt,
                                                   const float* __restrict__ ct,
                                                   float* __restrict__ outf) {
  int t = blockIdx.x, b = blockIdx.y;
  __shared__ float frp[3456];
  __shared__ float fl[NWIN];
  int tid = threadIdx.x;
  for (int i = tid; i < 3456; i += 256) frp[i] = 0.f;
  __syncthreads();
  // issue coalesced filter loads first (in flight under the scattered OLA reads)
  for (int i = tid; i < NWIN; i += 256) fl[i] = filt[((size_t)b * LF + t) * NWIN + i];
  for (int i = tid; i < FRAME; i += 256) {
    int n = t * FRAME + i;
    int p = n + 1920;
    int t0 = (p > 3839) ? ((p - 2880) / 960) : 0;
    int t1 = p / FRAME; if (t1 > 200) t1 = 200;
    float y = 0.f, wn = 0.f;
    for (int tt = t0; tt <= t1; ++tt) {
      int j = p - FRAME * tt;
      float w = 0.5f - 0.5f * ct[j];
      wn += w * w;
      if (tt >= 1) y += ft[((size_t)b * LF + (tt - 1)) * NFFT + j];
    }
    float den = wn > 1e-11f ? wn : 1.0f;
    float dspv = harm[(size_t)b * LW + n] + y / den;
    int x = 1024 + i;
    frp[x + (x >> 3)] = dspv;
  }
  __syncthreads();
  // per-wave nonzero tau8 band: wave w covers outputs [512w, 512w+512)
  // skip low tau8 where max sample idx 8*(tid+tau8)+14 < 1024  -> wave0 starts at 64
  // skip high tau8 where min sample idx 8*(tid+tau8) >= 1984   -> e8 = 248 - 64w
  int wv = tid >> 6;
  int s8 = (wv == 0) ? 64 : 0;
  int e8 = 248 - 64 * wv; if (e8 > 128) e8 = 128;
  float a[8] = {0.f, 0.f, 0.f, 0.f, 0.f, 0.f, 0.f, 0.f};
  float wbuf[8];
  int base = 9 * tid + 9 * s8;
#pragma unroll
  for (int r = 0; r < 8; ++r) wbuf[r] = frp[base + r];
  int nbase = base + 9;
  for (int t8 = s8; t8 < e8; ++t8) {
    int nb = nbase + (t8 - s8) * 9;
#pragma unroll
    for (int r = 0; r < 8; ++r) {
      float fv = fl[t8 * 8 + r];
#pragma unroll
      for (int q = 0; q < 8; ++q)
        a[q] = fmaf(wbuf[(r + q) & 7], fv, a[q]);
      wbuf[r] = frp[nb + r];
    }
  }
#pragma unroll
  for (int q = 0; q < 8; ++q) {
    int i = tid * 8 + q;
    if (i < 1984) outf[((size_t)b * LF + t) * 1984 + i] = a[q];
  }
}

// ---------------- fold (plain stores; overwrites every output element) ----------------
__global__ void fold_kernel(const float* __restrict__ outf, float* __restrict__ out) {
  int idx = blockIdx.x * 256 + threadIdx.x;
  if (idx >= NB * LW) return;
  int b = idx / LW, n = idx % LW;
  int t0 = (n >= 1984) ? ((n - 1024) / 960) : 0;
  int t1 = n / 960; if (t1 > 199) t1 = 199;
  float acc = 0.f;
  for (int t = t0; t <= t1; ++t)
    acc += outf[((size_t)b * LF + t) * 1984 + (n - 960 * t)];
  out[idx] = acc;
}

extern "C" void kernel_launch(void* const* d_in, const int* in_sizes, int n_in,
                              void* d_out, int out_size, void* d_ws, size_t ws_size,
                              hipStream_t stream) {
  const float* content    = (const float*)d_in[0];
  const float* f0         = (const float*)d_in[1];
  const float* energy     = (const float*)d_in[2];
  const float* spk        = (const float*)d_in[3];
  const float* s_in_w     = (const float*)d_in[4];
  const float* s_in_b     = (const float*)d_in[5];
  const float* s_dw_w     = (const float*)d_in[6];
  const float* s_dw_b     = (const float*)d_in[7];
  const float* s_ln       = (const float*)d_in[8];
  const float* s_pw1_w    = (const float*)d_in[9];
  const float* s_pw1_b    = (const float*)d_in[10];
  const float* s_pw2_w    = (const float*)d_in[11];
  const float* s_pw2_b    = (const float*)d_in[12];
  const float* s_out_norm = (const float*)d_in[13];
  const float* f_in_w     = (const float*)d_in[14];
  const float* f_in_b     = (const float*)d_in[15];
  const float* f_dw_w     = (const float*)d_in[16];
  const float* f_dw_b     = (const float*)d_in[17];
  const float* f_ln       = (const float*)d_in[18];
  const float* f_pw1_w    = (const float*)d_in[19];
  const float* f_pw1_b    = (const float*)d_in[20];
  const float* f_pw2_w    = (const float*)d_in[21];
  const float* f_pw2_b    = (const float*)d_in[22];
  const float* f_out_norm = (const float*)d_in[23];
  const float* s_in_norm  = (const float*)d_in[24];
  const float* s_amp_w    = (const float*)d_in[25];
  const float* s_amp_b    = (const float*)d_in[26];
  const float* s_ker_w    = (const float*)d_in[27];
  const float* s_ker_b    = (const float*)d_in[28];
  const float* f_out_w    = (const float*)d_in[29];
  const float* f_out_b    = (const float*)d_in[30];

  // ---- workspace layout (unchanged) ----
  char* W0 = (char*)d_ws;
  double*   CSUM  = (double*)W0;                         // 12,032
  uint32_t* XINPH = (uint32_t*)(W0 + 12032);             // 3,072,000
  float*    XS    = (float*)   (W0 + 6156032);           // 6,553,600 (3200 x 512)
  uint32_t* TPH   = (uint32_t*)(W0 + 12709632);          // 3,276,800 (3200 x 256)
  uint16_t* KERH  = (uint16_t*)(W0 + 19263232);          // 6,147,200
  float*    AMPS  = (float*)   (W0 + 25410432);          // 8,192
  float*    FILT  = (float*)   (W0 + 25418624);          // 6,553,600
  float*    HARM  = (float*)   (W0 + 31972224);          // 6,144,000
  char*     R2    = W0 + 38116224;                       // 26,411,008
  char*     FTR   = W0 + 64527232;                       // 24,576,000
  char*     U     = W0 + 89103232;                       // 25,559,040
  uint32_t* TH32  = (uint32_t*)(W0 + 114662272);         // 30,474,240  (pw2 packs -> T -> V)
  float*    CTAB  = (float*)   (W0 + 175610752);         // 15,360 -> ends 175,626,112
  // overlays
  uint32_t* XSPH = TPH;                                  // (after trunk, TP dead)
  uint32_t* H15PH = (uint32_t*)R2;                       // 9,830,400 (3200 x 768) hi-only
  uint32_t* IMPH = (uint32_t*)R2;                        // 11,468,800 (after H15 dead)
  uint16_t* SH   = (uint16_t*)R2;                        // 13,205,504 (1664 x 3968, after IMP dead)
  float*    OUTF = (float*)R2;                           // 12,697,600 (after SH dead post-invNT)
  float*    FS   = (float*)FTR;                          // 6,144,000
  float*    FT   = (float*)FTR;                          // 24,576,000 (after FS dead)
  // weight-pack blobs (hi only):
  uint32_t* PW1PH_A = (uint32_t*)FTR;                    // layers 0-2 (dead before FS)
  uint32_t* PW1PH_B = (uint32_t*)U;                      // layers 3-5 (dead before ker/fout packs)
  uint32_t* PW2PH = TH32;                                // pw2 all 6 layers (dead before twfill_pk)
  uint32_t* WINPH = (uint32_t*)R2;                       // in-proj pack (dead before H15)
  uint32_t* WPH  = (uint32_t*)U;                         // ker/fout packs, post-trunk
  uint16_t* AH   = (uint16_t*)U;                         // noise A hi (after WP dead)

  (void)in_sizes; (void)n_in; (void)out_size; (void)ws_size;

  ctab_fill<<<dim3(15), 256, 0, stream>>>(CTAB);
  build_xin_pk<<<dim3((MB2 * 240 + 255) / 256), 256, 0, stream>>>(content, f0, energy, spk, XINPH);

  // ---- mega-pack all trunk weights upfront (hi only) ----
  {
    int perset = HID * 256;
    int tot3 = 3 * 2 * perset;
    pack_wN<<<dim3((tot3 + 255) / 256), 256, 0, stream>>>(s_pw1_w, f_pw1_w, (size_t)HID * CI,
        PW1PH_A, HID, CI, 256, perset, tot3);
    pack_wN<<<dim3((tot3 + 255) / 256), 256, 0, stream>>>(s_pw1_w + (size_t)3 * HID * CI,
        f_pw1_w + (size_t)3 * HID * CI, (size_t)HID * CI,
        PW1PH_B, HID, CI, 256, perset, tot3);
    int tot6 = 6 * 2 * perset;
    pack_wN<<<dim3((tot6 + 255) / 256), 256, 0, stream>>>(s_pw2_w, f_pw2_w, (size_t)CI * HID,
        PW2PH, CI, HID, 768, perset, tot6);
  }
  {
    int total = CI * 240;
    pack_w2<<<dim3((2 * total + 255) / 256), 256, 0, stream>>>(s_in_w, f_in_w, WINPH, CI, CIN, 240, total);
  }

  // ---- batched dual-trunk (64x64 tiles, single-bf16) ----
  gemm_bf<<<dim3(8 * 50), 256, 0, stream>>>((uint16_t*)WINPH, (uint16_t*)XINPH,
      s_in_b, f_in_b, nullptr, XS, nullptr, CI, 480, 8, 50, 0, 0, 25, (size_t)512 * 480);
  ln2_kernel<<<dim3(MTOT / 4), 256, 0, stream>>>(XS, s_in_norm, s_in_norm + CI, nullptr);
  for (int i = 0; i < NL; ++i) {
    dwln_kernel<<<dim3(MB2), 256, 0, stream>>>(XS,
        s_dw_w + (size_t)i * CI * 7, s_dw_b + (size_t)i * CI,
        s_ln + (size_t)(i * 2) * CI, s_ln + (size_t)(i * 2 + 1) * CI,
        f_dw_w + (size_t)i * CI * 7, f_dw_b + (size_t)i * CI,
        f_ln + (size_t)(i * 2) * CI, f_ln + (size_t)(i * 2 + 1) * CI,
        TPH);
    const uint16_t* w1h = (i < 3) ? (const uint16_t*)((char*)PW1PH_A + (size_t)i * 3145728)
                                  : (const uint16_t*)((char*)PW1PH_B + (size_t)(i - 3) * 3145728);
    gemm_bf<<<dim3(24 * 50), 256, 0, stream>>>(w1h, (uint16_t*)TPH,
        s_pw1_b + (size_t)i * HID, f_pw1_b + (size_t)i * HID, nullptr,
        nullptr, (uint16_t*)H15PH, HID, 512, 24, 50, 1, 1, 25, (size_t)1536 * 512);
    const uint16_t* w2h = (const uint16_t*)((char*)PW2PH + (size_t)i * 3145728);
    gemm_bf<<<dim3(8 * 50), 256, 0, stream>>>(w2h, (uint16_t*)H15PH,
        s_pw2_b + (size_t)i * CI, f_pw2_b + (size_t)i * CI, XS,
        XS, nullptr, CI, 1536, 8, 50, 0, 0, 25, (size_t)512 * 1536);
  }

  // ---- heads ----
  ln2_kernel<<<dim3(MTOT / 4), 256, 0, stream>>>(XS, s_out_norm, s_out_norm + CI, XSPH);
  amps2_kernel<<<dim3(MTOT / 4), 256, 0, stream>>>(XS, s_amp_w, s_amp_b, AMPS);
  {
    int total = 1984 * 256;
    pack_w<<<dim3((total + 255) / 256), 256, 0, stream>>>(s_ker_w, WPH, NFREQ, CI, 256, total);
  }
  gemm_bf<<<dim3(31 * 25), 256, 0, stream>>>((uint16_t*)WPH, (uint16_t*)XSPH,
      s_ker_b, nullptr, nullptr, nullptr, KERH, NFREQ, 512, 31, 25, 2, 2, 1000, 0);

  ln2_kernel<<<dim3(MTOT / 4), 256, 0, stream>>>(XS + (size_t)MTOT * CI, f_out_norm, f_out_norm + CI, nullptr);
  im2col_pk<<<dim3((MTOT * 1792 + 255) / 256), 256, 0, stream>>>(XS + (size_t)MTOT * CI, IMPH);
  {
    int total = NWIN * 1792;
    pack_w<<<dim3((total + 255) / 256), 256, 0, stream>>>(f_out_w, WPH, NWIN, 3584, 1792, total);
  }
  gemm_bf<<<dim3(16 * 25), 256, 0, stream>>>((uint16_t*)WPH, (uint16_t*)IMPH,
      f_out_b, nullptr, nullptr, FILT, nullptr, NWIN, 3584, 16, 25, 0, 0, 1000, 0);

  // ---- harmonic source (FS lives in FT region, dead before inv) ----
  cumsum1<<<dim3(NCH, NB), 256, 0, stream>>>(f0, FS, CSUM);
  harm_kernel<<<dim3(NCH, NB), 256, 0, stream>>>(FS, CSUM, f0, AMPS, HARM);

  // ---- filtered noise: fwd (T table) then inv (V table overwrites T), single-bf16, 128x128 x 512thr ----
  pack_noise<<<dim3((MPAD * 1920 + 255) / 256), 256, 0, stream>>>(CTAB, (uint32_t*)AH);
  twfill_pk<<<dim3((SWID * 1920 + 255) / 256), 256, 0, stream>>>(CTAB, TH32);
  gemm_fwd128<<<dim3(13 * 31), 512, 0, stream>>>((uint16_t*)AH, (uint16_t*)TH32, KERH, SH);
  twfill_v<<<dim3((NFFT * (SWID / 2) + 255) / 256), 256, 0, stream>>>(CTAB, TH32);
  gemm_invNT<<<dim3(30 * 13), 512, 0, stream>>>(SH, (uint16_t*)TH32, CTAB, FT);

  // ---- fused OLA + FIR (wave-bounded taps) + fold ----
  fir5_kernel<<<dim3(LF, NB), 256, 0, stream>>>(FT, HARM, FILT, CTAB, OUTF);
  fold_kernel<<<dim3((NB * LW + 255) / 256), 256, 0, stream>>>(OUTF, (float*)d_out);
}